// Round 1
// baseline (8984.290 us; speedup 1.0000x reference)
//
#include <hip/hip_runtime.h>
#include <math.h>

#define BB 16
#define KK 4
#define VV 32000
#define DD 512
#define LL 32
#define EOS_ID 2
#define NEGINF 1.0e7f
#define ALPHA_C 0.6f

// ---------------- init ----------------
__global__ void k_init(const int* __restrict__ initial_ids,
                       const float* __restrict__ init_h,
                       float* cache_h, int* alive_seq, float* alive_lp,
                       int* fin_seq, float* fin_sc, int* fin_fl) {
    int tid = blockIdx.x * blockDim.x + threadIdx.x;
    int nthreads = gridDim.x * blockDim.x;
    const int SEQ = BB * KK * (LL + 1);
    for (int idx = tid; idx < SEQ; idx += nthreads) {
        int pos = idx % (LL + 1);
        int bk = idx / (LL + 1);
        int b = bk / KK;
        alive_seq[idx] = (pos == 0) ? initial_ids[b] : 0;
        fin_seq[idx] = 0;
    }
    for (int idx = tid; idx < BB * KK; idx += nthreads) {
        int k = idx % KK;
        alive_lp[idx] = (k == 0) ? 0.0f : -NEGINF;
        fin_sc[idx] = -NEGINF;
        fin_fl[idx] = 0;
    }
    for (int idx = tid; idx < BB * KK * DD; idx += nthreads) {
        int d = idx % DD;
        int b = idx / (KK * DD);
        cache_h[idx] = init_h[b * DD + d];
    }
}

// ---------------- logits: h = tanh(cache+embed[last]); logits = h @ proj ----------------
// grid (32, BB), block 256. Each block: batch b, 1000 columns. 250 active threads x 4 cols.
#define VC 1000
__global__ __launch_bounds__(256) void k_logits(
        const float* __restrict__ embed, const float* __restrict__ proj,
        const float* __restrict__ cache_h, const int* __restrict__ alive_seq,
        float* __restrict__ logits, int step) {
    int b = blockIdx.y;
    int chunk = blockIdx.x;
    int t = threadIdx.x;
    __shared__ float h_lds[KK][DD];
    __shared__ int toks[KK];
    if (t < KK) toks[t] = alive_seq[(b * KK + t) * (LL + 1) + step];
    __syncthreads();
    for (int idx = t; idx < KK * DD; idx += 256) {
        int k = idx >> 9;           // DD = 512
        int d = idx & (DD - 1);
        h_lds[k][d] = tanhf(cache_h[(b * KK + k) * DD + d] +
                            embed[(size_t)toks[k] * DD + d]);
    }
    __syncthreads();
    if (t >= VC / 4) return;
    int c0 = chunk * VC + t * 4;
    float acc[KK][4];
    #pragma unroll
    for (int k = 0; k < KK; k++)
        #pragma unroll
        for (int c = 0; c < 4; c++) acc[k][c] = 0.0f;
    for (int d = 0; d < DD; d += 4) {
        float4 h4[KK];
        #pragma unroll
        for (int k = 0; k < KK; k++)
            h4[k] = *reinterpret_cast<const float4*>(&h_lds[k][d]);
        #pragma unroll
        for (int j = 0; j < 4; j++) {
            float4 p = *reinterpret_cast<const float4*>(&proj[(size_t)(d + j) * VV + c0]);
            #pragma unroll
            for (int k = 0; k < KK; k++) {
                float hv = (j == 0) ? h4[k].x : (j == 1) ? h4[k].y
                         : (j == 2) ? h4[k].z : h4[k].w;
                acc[k][0] = fmaf(hv, p.x, acc[k][0]);
                acc[k][1] = fmaf(hv, p.y, acc[k][1]);
                acc[k][2] = fmaf(hv, p.z, acc[k][2]);
                acc[k][3] = fmaf(hv, p.w, acc[k][3]);
            }
        }
    }
    #pragma unroll
    for (int k = 0; k < KK; k++) {
        float4 o = make_float4(acc[k][0], acc[k][1], acc[k][2], acc[k][3]);
        *reinterpret_cast<float4*>(&logits[((size_t)(b * KK + k)) * VV + c0]) = o;
    }
}

// ---------------- per-row reduce: stable top-8 + logsumexp ----------------
// grid BB*KK, block 256
__global__ __launch_bounds__(256) void k_rowreduce(
        const float* __restrict__ logits,
        float* __restrict__ rowtop_val, int* __restrict__ rowtop_idx,
        float* __restrict__ row_lse) {
    int row = blockIdx.x;
    int t = threadIdx.x;
    const float* lg = logits + (size_t)row * VV;

    float lv[8]; int li[8];
    #pragma unroll
    for (int j = 0; j < 8; j++) { lv[j] = -INFINITY; li[j] = 0x7fffffff; }
    for (int c = t; c < VV; c += 256) {
        float v = lg[c];
        if (v > lv[7]) {
            int j = 7;
            while (j > 0 && v > lv[j - 1]) { lv[j] = lv[j - 1]; li[j] = li[j - 1]; j--; }
            lv[j] = v; li[j] = c;   // strict > keeps earlier (lower) index first on ties
        }
    }
    __shared__ float sval[256][8];
    __shared__ int   sidx[256][8];
    #pragma unroll
    for (int j = 0; j < 8; j++) { sval[t][j] = lv[j]; sidx[t][j] = li[j]; }
    __syncthreads();
    for (int s = 128; s > 0; s >>= 1) {
        if (t < s) {
            float rv[8]; int ri[8];
            int pa = 0, pb = 0;
            #pragma unroll
            for (int j = 0; j < 8; j++) {
                bool aok = pa < 8, bok = pb < 8;
                float va = sval[t][aok ? pa : 7],     vb = sval[t + s][bok ? pb : 7];
                int   ia = sidx[t][aok ? pa : 7],     ib = sidx[t + s][bok ? pb : 7];
                bool takeA = !bok || (aok && ((va > vb) || (va == vb && ia <= ib)));
                if (takeA) { rv[j] = va; ri[j] = ia; pa++; }
                else       { rv[j] = vb; ri[j] = ib; pb++; }
            }
            #pragma unroll
            for (int j = 0; j < 8; j++) { sval[t][j] = rv[j]; sidx[t][j] = ri[j]; }
        }
        __syncthreads();
    }
    float rowmax = sval[0][0];
    float s = 0.0f;
    for (int c = t; c < VV; c += 256) s += expf(lg[c] - rowmax);
    __shared__ float red[256];
    red[t] = s; __syncthreads();
    for (int st = 128; st > 0; st >>= 1) {
        if (t < st) red[t] += red[t + st];
        __syncthreads();
    }
    if (t == 0) {
        #pragma unroll
        for (int j = 0; j < 8; j++) {
            rowtop_val[row * 8 + j] = sval[0][j];
            rowtop_idx[row * 8 + j] = sidx[0][j];
        }
        row_lse[row] = rowmax + logf(red[0]);
    }
}

// ---------------- beam update ----------------
// grid BB, block 256
__global__ __launch_bounds__(256) void k_update(
        const float* __restrict__ embed,
        float* cache_h, int* alive_seq, float* alive_lp,
        int* fin_seq, float* fin_sc, int* fin_fl,
        const float* __restrict__ rowtop_val, const int* __restrict__ rowtop_idx,
        const float* __restrict__ row_lse, int step) {
    int b = blockIdx.x;
    int t = threadIdx.x;
    __shared__ float c_lp[8];
    __shared__ int   c_beam[8], c_id[8], c_fl[8];
    __shared__ int   sel_alive[KK];
    __shared__ float n_alive_lp_s[KK];
    __shared__ int   sel_fin_src[KK];
    __shared__ float n_fin_sc_s[KK];
    __shared__ int   n_fin_fl_s[KK];
    __shared__ int   old_aseq[KK][LL + 1];
    __shared__ int   old_fseq[KK][LL + 1];
    __shared__ float newh[KK][DD];

    for (int idx = t; idx < KK * (LL + 1); idx += 256) {
        old_aseq[idx / (LL + 1)][idx % (LL + 1)] = alive_seq[b * KK * (LL + 1) + idx];
        old_fseq[idx / (LL + 1)][idx % (LL + 1)] = fin_seq[b * KK * (LL + 1) + idx];
    }
    __syncthreads();

    if (t == 0) {
        // 32 candidates: lp = (rowtop - lse) + alive_lp ; tie key = k*V + tok
        float cv[32]; int ck[32], ctok[32];
        for (int k = 0; k < KK; k++) {
            float lse = row_lse[b * KK + k];
            float alp = alive_lp[b * KK + k];
            for (int j = 0; j < 8; j++) {
                int idx = k * 8 + j;
                cv[idx] = (rowtop_val[(b * KK + k) * 8 + j] - lse) + alp;
                ctok[idx] = rowtop_idx[(b * KK + k) * 8 + j];
                ck[idx] = k;
            }
        }
        bool used[32];
        for (int i2 = 0; i2 < 32; i2++) used[i2] = false;
        for (int sel = 0; sel < 8; sel++) {
            int best = -1;
            for (int idx = 0; idx < 32; idx++) {
                if (used[idx]) continue;
                if (best < 0) { best = idx; continue; }
                long long gi = (long long)ck[idx] * VV + ctok[idx];
                long long gb = (long long)ck[best] * VV + ctok[best];
                if (cv[idx] > cv[best] || (cv[idx] == cv[best] && gi < gb)) best = idx;
            }
            used[best] = true;
            c_lp[sel] = cv[best]; c_beam[sel] = ck[best]; c_id[sel] = ctok[best];
            c_fl[sel] = (ctok[best] == EOS_ID) ? 1 : 0;
        }
        // alive: stable top-4 of alive_sc over the 8 candidates
        float asc[8];
        for (int j = 0; j < 8; j++) asc[j] = c_lp[j] + (c_fl[j] ? -NEGINF : 0.0f);
        bool u2[8]; for (int j = 0; j < 8; j++) u2[j] = false;
        for (int sel = 0; sel < KK; sel++) {
            int best = -1;
            for (int j = 0; j < 8; j++) {
                if (u2[j]) continue;
                if (best < 0 || asc[j] > asc[best]) best = j;  // ties: lower j kept
            }
            u2[best] = true;
            sel_alive[sel] = best;
            n_alive_lp_s[sel] = asc[best];
        }
        // finished: comb = [fin_sc(4) ; new_scores(8)], stable top-4
        float ln = powf((6.0f + (float)step) / 6.0f, ALPHA_C);
        float comb[12]; int combfl[12];
        for (int j = 0; j < KK; j++) { comb[j] = fin_sc[b * KK + j]; combfl[j] = fin_fl[b * KK + j]; }
        for (int j = 0; j < 8; j++) {
            comb[4 + j] = c_lp[j] / ln + (c_fl[j] ? 0.0f : -NEGINF);
            combfl[4 + j] = c_fl[j];
        }
        bool u3[12]; for (int j = 0; j < 12; j++) u3[j] = false;
        for (int sel = 0; sel < KK; sel++) {
            int best = -1;
            for (int j = 0; j < 12; j++) {
                if (u3[j]) continue;
                if (best < 0 || comb[j] > comb[best]) best = j;  // ties: lower j
            }
            u3[best] = true;
            sel_fin_src[sel] = best;
            n_fin_sc_s[sel] = comb[best];
            n_fin_fl_s[sel] = combfl[best];
        }
    }
    __syncthreads();

    // new sequences
    for (int idx = t; idx < KK * (LL + 1); idx += 256) {
        int j = idx / (LL + 1), p = idx % (LL + 1);
        int cand = sel_alive[j];
        int bm = c_beam[cand];
        int val = (p == step + 1) ? c_id[cand] : old_aseq[bm][p];
        alive_seq[b * KK * (LL + 1) + idx] = val;
        int src = sel_fin_src[j];
        int fval;
        if (src < 4) fval = old_fseq[src][p];
        else {
            int c2 = src - 4, bm2 = c_beam[c2];
            fval = (p == step + 1) ? c_id[c2] : old_aseq[bm2][p];
        }
        fin_seq[b * KK * (LL + 1) + idx] = fval;
    }
    // new cache = h[selected beams] recomputed from OLD cache
    for (int idx = t; idx < KK * DD; idx += 256) {
        int j = idx >> 9, d = idx & (DD - 1);
        int cand = sel_alive[j];
        int bm = c_beam[cand];
        int tok = old_aseq[bm][step];
        newh[j][d] = tanhf(cache_h[(b * KK + bm) * DD + d] +
                           embed[(size_t)tok * DD + d]);
    }
    __syncthreads();
    for (int idx = t; idx < KK * DD; idx += 256) {
        int j = idx >> 9, d = idx & (DD - 1);
        cache_h[(b * KK + j) * DD + d] = newh[j][d];
    }
    if (t < KK) {
        alive_lp[b * KK + t] = n_alive_lp_s[t];
        fin_sc[b * KK + t] = n_fin_sc_s[t];
        fin_fl[b * KK + t] = n_fin_fl_s[t];
    }
}

// ---------------- finalize ----------------
__global__ void k_final(const int* __restrict__ alive_seq, const float* __restrict__ alive_lp,
                        const int* __restrict__ fin_seq, const float* __restrict__ fin_sc,
                        const int* __restrict__ fin_fl, float* __restrict__ out) {
    int b = blockIdx.x;
    int t = threadIdx.x;
    __shared__ int anyf;
    if (t == 0)
        anyf = fin_fl[b * KK] | fin_fl[b * KK + 1] | fin_fl[b * KK + 2] | fin_fl[b * KK + 3];
    __syncthreads();
    for (int idx = t; idx < KK * (LL + 1); idx += blockDim.x) {
        int src = anyf ? fin_seq[b * KK * (LL + 1) + idx] : alive_seq[b * KK * (LL + 1) + idx];
        out[b * KK * (LL + 1) + idx] = (float)src;
    }
    if (t < KK)
        out[BB * KK * (LL + 1) + b * KK + t] = anyf ? fin_sc[b * KK + t] : alive_lp[b * KK + t];
}

extern "C" void kernel_launch(void* const* d_in, const int* in_sizes, int n_in,
                              void* d_out, int out_size, void* d_ws, size_t ws_size,
                              hipStream_t stream) {
    const int* initial_ids = (const int*)d_in[0];
    const float* init_h = (const float*)d_in[1];
    const float* embed = (const float*)d_in[2];
    const float* proj = (const float*)d_in[3];
    float* out = (float*)d_out;

    char* ws = (char*)d_ws;
    size_t off = 0;
    auto alloc = [&](size_t bytes) -> void* {
        off = (off + 255) & ~(size_t)255;
        void* p = ws + off;
        off += bytes;
        return p;
    };
    int* alive_seq   = (int*)alloc((size_t)BB * KK * (LL + 1) * 4);
    int* fin_seq     = (int*)alloc((size_t)BB * KK * (LL + 1) * 4);
    float* alive_lp  = (float*)alloc((size_t)BB * KK * 4);
    float* fin_sc    = (float*)alloc((size_t)BB * KK * 4);
    int* fin_fl      = (int*)alloc((size_t)BB * KK * 4);
    float* cache_h   = (float*)alloc((size_t)BB * KK * DD * 4);
    float* logits    = (float*)alloc((size_t)BB * KK * VV * 4);
    float* rowtop_val= (float*)alloc((size_t)BB * KK * 8 * 4);
    int* rowtop_idx  = (int*)alloc((size_t)BB * KK * 8 * 4);
    float* row_lse   = (float*)alloc((size_t)BB * KK * 4);

    k_init<<<128, 256, 0, stream>>>(initial_ids, init_h, cache_h,
                                    alive_seq, alive_lp, fin_seq, fin_sc, fin_fl);
    for (int step = 0; step < LL; step++) {
        k_logits<<<dim3(32, BB), 256, 0, stream>>>(embed, proj, cache_h, alive_seq,
                                                   logits, step);
        k_rowreduce<<<BB * KK, 256, 0, stream>>>(logits, rowtop_val, rowtop_idx, row_lse);
        k_update<<<BB, 256, 0, stream>>>(embed, cache_h, alive_seq, alive_lp,
                                         fin_seq, fin_sc, fin_fl,
                                         rowtop_val, rowtop_idx, row_lse, step);
    }
    k_final<<<BB, 64, 0, stream>>>(alive_seq, alive_lp, fin_seq, fin_sc, fin_fl, out);
}

// Round 2
// 3655.562 us; speedup vs baseline: 2.4577x; 2.4577x over previous
//
#include <hip/hip_runtime.h>
#include <math.h>

#define BB 16
#define KK 4
#define VV 32000
#define DD 512
#define LL 32
#define EOS_ID 2
#define NEGINF 1.0e7f
#define ALPHA_C 0.6f
#define NROW (BB * KK)        // 64
#define NCHUNK 4
#define CHSZ (VV / NCHUNK)    // 8000

// ---------------- init: sequences / scores ----------------
__global__ void k_init(const int* __restrict__ initial_ids,
                       int* alive_seq, float* alive_lp,
                       int* fin_seq, float* fin_sc, int* fin_fl) {
    int tid = blockIdx.x * blockDim.x + threadIdx.x;
    int nthreads = gridDim.x * blockDim.x;
    const int SEQ = NROW * (LL + 1);
    for (int idx = tid; idx < SEQ; idx += nthreads) {
        int pos = idx % (LL + 1);
        int b = (idx / (LL + 1)) / KK;
        alive_seq[idx] = (pos == 0) ? initial_ids[b] : 0;
        fin_seq[idx] = 0;
    }
    for (int idx = tid; idx < NROW; idx += nthreads) {
        int k = idx % KK;
        alive_lp[idx] = (k == 0) ? 0.0f : -NEGINF;
        fin_sc[idx] = -NEGINF;
        fin_fl[idx] = 0;
    }
}

// ---------------- initial h: h = tanh(init_h + embed[tok0]) ----------------
__global__ void k_hinit(const int* __restrict__ initial_ids,
                        const float* __restrict__ init_h,
                        const float* __restrict__ embed,
                        float* __restrict__ h_buf) {
    int row = blockIdx.x;
    int b = row >> 2;
    int t = threadIdx.x;
    int tok = initial_ids[b];
    for (int d = t; d < DD; d += 256)
        h_buf[row * DD + d] = tanhf(init_h[b * DD + d] + embed[(size_t)tok * DD + d]);
}

// ---------------- logits = h_buf(64x512) @ proj(512x32000) ----------------
// grid 250, block 256. Block: 128 cols x all 64 rows. Wave w: rows 16w..16w+16.
// Thread: 2 cols x 16 rows, fp32 acc. proj read exactly once per step chip-wide.
__global__ __launch_bounds__(256) void k_logits(
        const float* __restrict__ proj, const float* __restrict__ h_buf,
        float* __restrict__ logits) {
    int t = threadIdx.x;
    int w = t >> 6, l = t & 63;
    int c = blockIdx.x * 128 + l * 2;
    int r0 = w * 16;
    __shared__ float h_tile[NROW][128];
    float acc[16][2];
    #pragma unroll
    for (int r = 0; r < 16; r++) { acc[r][0] = 0.0f; acc[r][1] = 0.0f; }

    for (int d0 = 0; d0 < DD; d0 += 128) {
        __syncthreads();
        #pragma unroll
        for (int i = 0; i < 8; i++) {
            int e = (i * 256 + t) * 4;
            int r = e >> 7, dd = e & 127;
            *reinterpret_cast<float4*>(&h_tile[r][dd]) =
                *reinterpret_cast<const float4*>(&h_buf[r * DD + d0 + dd]);
        }
        __syncthreads();
        for (int dd = 0; dd < 128; dd += 4) {
            float4 h4[16];
            #pragma unroll
            for (int r = 0; r < 16; r++)
                h4[r] = *reinterpret_cast<const float4*>(&h_tile[r0 + r][dd]);
            #pragma unroll
            for (int j = 0; j < 4; j++) {
                float2 p2 = *reinterpret_cast<const float2*>(
                    &proj[(size_t)(d0 + dd + j) * VV + c]);
                #pragma unroll
                for (int r = 0; r < 16; r++) {
                    float hv = (j == 0) ? h4[r].x : (j == 1) ? h4[r].y
                             : (j == 2) ? h4[r].z : h4[r].w;
                    acc[r][0] = fmaf(hv, p2.x, acc[r][0]);
                    acc[r][1] = fmaf(hv, p2.y, acc[r][1]);
                }
            }
        }
    }
    #pragma unroll
    for (int r = 0; r < 16; r++) {
        float2 o = make_float2(acc[r][0], acc[r][1]);
        *reinterpret_cast<float2*>(&logits[(size_t)(r0 + r) * VV + c]) = o;
    }
}

// ---------------- per (row, col-chunk): stable top-8 + partial max/expsum ----------------
// grid (NCHUNK, NROW), block 256
__global__ __launch_bounds__(256) void k_rowpart(
        const float* __restrict__ logits,
        float* __restrict__ ptop_val, int* __restrict__ ptop_idx,
        float* __restrict__ pmax, float* __restrict__ psum) {
    int chunk = blockIdx.x;
    int row = blockIdx.y;
    int t = threadIdx.x;
    const float* lg = logits + (size_t)row * VV;
    int cbeg = chunk * CHSZ, cend = cbeg + CHSZ;

    float lv[8]; int li[8];
    #pragma unroll
    for (int j = 0; j < 8; j++) { lv[j] = -INFINITY; li[j] = 0x7fffffff; }
    for (int c = cbeg + t; c < cend; c += 256) {
        float v = lg[c];
        if (v > lv[7]) {
            int j = 7;
            while (j > 0 && v > lv[j - 1]) { lv[j] = lv[j - 1]; li[j] = li[j - 1]; j--; }
            lv[j] = v; li[j] = c;   // strict >: equal values keep earlier index first
        }
    }
    __shared__ float sval[256][8];
    __shared__ int   sidx[256][8];
    #pragma unroll
    for (int j = 0; j < 8; j++) { sval[t][j] = lv[j]; sidx[t][j] = li[j]; }
    __syncthreads();
    for (int s = 128; s > 0; s >>= 1) {
        if (t < s) {
            float rv[8]; int ri[8];
            int pa = 0, pb = 0;
            #pragma unroll
            for (int j = 0; j < 8; j++) {
                bool aok = pa < 8, bok = pb < 8;
                float va = sval[t][aok ? pa : 7],     vb = sval[t + s][bok ? pb : 7];
                int   ia = sidx[t][aok ? pa : 7],     ib = sidx[t + s][bok ? pb : 7];
                bool takeA = !bok || (aok && ((va > vb) || (va == vb && ia <= ib)));
                if (takeA) { rv[j] = va; ri[j] = ia; pa++; }
                else       { rv[j] = vb; ri[j] = ib; pb++; }
            }
            #pragma unroll
            for (int j = 0; j < 8; j++) { sval[t][j] = rv[j]; sidx[t][j] = ri[j]; }
        }
        __syncthreads();
    }
    float m = sval[0][0];   // chunk max
    float s = 0.0f;
    for (int c = cbeg + t; c < cend; c += 256) s += expf(lg[c] - m);
    __shared__ float red[256];
    red[t] = s; __syncthreads();
    for (int st = 128; st > 0; st >>= 1) {
        if (t < st) red[t] += red[t + st];
        __syncthreads();
    }
    if (t == 0) {
        #pragma unroll
        for (int j = 0; j < 8; j++) {
            ptop_val[(row * NCHUNK + chunk) * 8 + j] = sval[0][j];
            ptop_idx[(row * NCHUNK + chunk) * 8 + j] = sidx[0][j];
        }
        pmax[row * NCHUNK + chunk] = m;
        psum[row * NCHUNK + chunk] = red[0];
    }
}

// ---------------- beam update: fully parallel rank-based selection ----------------
// grid BB, block 256
__global__ __launch_bounds__(256) void k_update(
        const float* __restrict__ embed,
        float* h_buf, int* alive_seq, float* alive_lp,
        int* fin_seq, float* fin_sc, int* fin_fl,
        const float* __restrict__ ptop_val, const int* __restrict__ ptop_idx,
        const float* __restrict__ pmax, const float* __restrict__ psum, int step) {
    int b = blockIdx.x;
    int t = threadIdx.x;
    __shared__ float h_old[KK][DD];
    __shared__ int old_aseq[KK][LL + 1], old_fseq[KK][LL + 1];
    __shared__ float lse_s[KK], alp_s[KK];
    __shared__ float clp[128]; __shared__ int cidx[128];
    __shared__ float c_lp[8];  __shared__ int c_beam[8], c_id[8], c_fl[8];
    __shared__ float asc_s[8], comb_s[12]; __shared__ int combfl_s[12];
    __shared__ int sel_alive[KK], sel_fin[KK];
    __shared__ float n_alp[KK], n_fsc[KK]; __shared__ int n_ffl[KK];

    for (int idx = t; idx < KK * (LL + 1); idx += 256) {
        old_aseq[idx / (LL + 1)][idx % (LL + 1)] = alive_seq[b * KK * (LL + 1) + idx];
        old_fseq[idx / (LL + 1)][idx % (LL + 1)] = fin_seq[b * KK * (LL + 1) + idx];
    }
    for (int idx = t; idx < KK * DD; idx += 256)
        h_old[idx >> 9][idx & (DD - 1)] = h_buf[b * KK * DD + idx];
    if (t < KK) {
        int r = b * KK + t;
        float m = fmaxf(fmaxf(pmax[r * 4 + 0], pmax[r * 4 + 1]),
                        fmaxf(pmax[r * 4 + 2], pmax[r * 4 + 3]));
        float s = 0.0f;
        #pragma unroll
        for (int c2 = 0; c2 < 4; c2++) s += psum[r * 4 + c2] * expf(pmax[r * 4 + c2] - m);
        lse_s[t] = m + logf(s);
        alp_s[t] = alive_lp[r];
    }
    __syncthreads();

    // 128 candidates = 4 rows x 4 chunks x 8. lp = logit - lse + alive_lp.
    if (t < 128) {
        int row = t >> 5;
        int src = ((b * KK + row) * NCHUNK + ((t >> 3) & 3)) * 8 + (t & 7);
        clp[t] = ptop_val[src] - lse_s[row] + alp_s[row];
        cidx[t] = ptop_idx[src];
    }
    __syncthreads();
    // stable rank over all 128 (tie key = row*V + token, ascending) -> top-8
    if (t < 128) {
        int row = t >> 5;
        float mylp = clp[t];
        int mykey = row * VV + cidx[t];
        int cnt = 0;
        for (int j = 0; j < 128; j++) {
            float lj = clp[j];
            int kj = (j >> 5) * VV + cidx[j];
            cnt += (lj > mylp) || (lj == mylp && kj < mykey);
        }
        if (cnt < 8) {
            c_lp[cnt] = mylp; c_beam[cnt] = row; c_id[cnt] = cidx[t];
            c_fl[cnt] = (cidx[t] == EOS_ID) ? 1 : 0;
        }
    }
    __syncthreads();
    if (t < 8) asc_s[t] = c_lp[t] + (c_fl[t] ? -NEGINF : 0.0f);
    if (t >= 64 && t < 76) {
        int j2 = t - 64;
        if (j2 < 4) { comb_s[j2] = fin_sc[b * KK + j2]; combfl_s[j2] = fin_fl[b * KK + j2]; }
        else {
            int cc = j2 - 4;
            float ln = powf((6.0f + (float)step) / 6.0f, ALPHA_C);
            comb_s[j2] = c_lp[cc] / ln + (c_fl[cc] ? 0.0f : -NEGINF);
            combfl_s[j2] = c_fl[cc];
        }
    }
    __syncthreads();
    if (t < 8) {   // alive: stable top-4 of asc (ties: lower position)
        float a = asc_s[t];
        int cnt = 0;
        #pragma unroll
        for (int j = 0; j < 8; j++) cnt += (asc_s[j] > a) || (asc_s[j] == a && j < t);
        if (cnt < KK) { sel_alive[cnt] = t; n_alp[cnt] = a; }
    }
    if (t >= 64 && t < 76) {  // finished: stable top-4 of comb (ties: lower position)
        int j2 = t - 64;
        float cval = comb_s[j2];
        int cnt = 0;
        #pragma unroll
        for (int j = 0; j < 12; j++) cnt += (comb_s[j] > cval) || (comb_s[j] == cval && j < j2);
        if (cnt < KK) { sel_fin[cnt] = j2; n_fsc[cnt] = cval; n_ffl[cnt] = combfl_s[j2]; }
    }
    __syncthreads();

    // write new sequences
    for (int idx = t; idx < KK * (LL + 1); idx += 256) {
        int j = idx / (LL + 1), p = idx % (LL + 1);
        int cand = sel_alive[j], bm = c_beam[cand];
        alive_seq[b * KK * (LL + 1) + idx] = (p == step + 1) ? c_id[cand] : old_aseq[bm][p];
        int src = sel_fin[j];
        int fval;
        if (src < 4) fval = old_fseq[src][p];
        else {
            int c2 = src - 4, bm2 = c_beam[c2];
            fval = (p == step + 1) ? c_id[c2] : old_aseq[bm2][p];
        }
        fin_seq[b * KK * (LL + 1) + idx] = fval;
    }
    // next-step h: h' = tanh(h_old[selected beam] + embed[new token])
    for (int idx = t; idx < KK * DD; idx += 256) {
        int j = idx >> 9, d = idx & (DD - 1);
        int cand = sel_alive[j], bm = c_beam[cand], tok = c_id[cand];
        h_buf[(b * KK + j) * DD + d] = tanhf(h_old[bm][d] + embed[(size_t)tok * DD + d]);
    }
    if (t < KK) {
        alive_lp[b * KK + t] = n_alp[t];
        fin_sc[b * KK + t] = n_fsc[t];
        fin_fl[b * KK + t] = n_ffl[t];
    }
}

// ---------------- finalize ----------------
__global__ void k_final(const int* __restrict__ alive_seq, const float* __restrict__ alive_lp,
                        const int* __restrict__ fin_seq, const float* __restrict__ fin_sc,
                        const int* __restrict__ fin_fl, float* __restrict__ out) {
    int b = blockIdx.x;
    int t = threadIdx.x;
    __shared__ int anyf;
    if (t == 0)
        anyf = fin_fl[b * KK] | fin_fl[b * KK + 1] | fin_fl[b * KK + 2] | fin_fl[b * KK + 3];
    __syncthreads();
    for (int idx = t; idx < KK * (LL + 1); idx += blockDim.x) {
        int src = anyf ? fin_seq[b * KK * (LL + 1) + idx] : alive_seq[b * KK * (LL + 1) + idx];
        out[b * KK * (LL + 1) + idx] = (float)src;
    }
    if (t < KK)
        out[BB * KK * (LL + 1) + b * KK + t] = anyf ? fin_sc[b * KK + t] : alive_lp[b * KK + t];
}

extern "C" void kernel_launch(void* const* d_in, const int* in_sizes, int n_in,
                              void* d_out, int out_size, void* d_ws, size_t ws_size,
                              hipStream_t stream) {
    const int* initial_ids = (const int*)d_in[0];
    const float* init_h = (const float*)d_in[1];
    const float* embed = (const float*)d_in[2];
    const float* proj = (const float*)d_in[3];
    float* out = (float*)d_out;

    char* ws = (char*)d_ws;
    size_t off = 0;
    auto alloc = [&](size_t bytes) -> void* {
        off = (off + 255) & ~(size_t)255;
        void* p = ws + off;
        off += bytes;
        return p;
    };
    int* alive_seq    = (int*)alloc((size_t)NROW * (LL + 1) * 4);
    int* fin_seq      = (int*)alloc((size_t)NROW * (LL + 1) * 4);
    float* alive_lp   = (float*)alloc((size_t)NROW * 4);
    float* fin_sc     = (float*)alloc((size_t)NROW * 4);
    int* fin_fl       = (int*)alloc((size_t)NROW * 4);
    float* h_buf      = (float*)alloc((size_t)NROW * DD * 4);
    float* logits     = (float*)alloc((size_t)NROW * VV * 4);
    float* ptop_val   = (float*)alloc((size_t)NROW * NCHUNK * 8 * 4);
    int* ptop_idx     = (int*)alloc((size_t)NROW * NCHUNK * 8 * 4);
    float* pmax       = (float*)alloc((size_t)NROW * NCHUNK * 4);
    float* psum       = (float*)alloc((size_t)NROW * NCHUNK * 4);

    k_init<<<16, 256, 0, stream>>>(initial_ids, alive_seq, alive_lp,
                                   fin_seq, fin_sc, fin_fl);
    k_hinit<<<NROW, 256, 0, stream>>>(initial_ids, init_h, embed, h_buf);
    for (int step = 0; step < LL; step++) {
        k_logits<<<250, 256, 0, stream>>>(proj, h_buf, logits);
        k_rowpart<<<dim3(NCHUNK, NROW), 256, 0, stream>>>(logits, ptop_val, ptop_idx,
                                                          pmax, psum);
        k_update<<<BB, 256, 0, stream>>>(embed, h_buf, alive_seq, alive_lp,
                                         fin_seq, fin_sc, fin_fl,
                                         ptop_val, ptop_idx, pmax, psum, step);
    }
    k_final<<<BB, 64, 0, stream>>>(alive_seq, alive_lp, fin_seq, fin_sc, fin_fl, out);
}

// Round 3
// 2112.247 us; speedup vs baseline: 4.2534x; 1.7307x over previous
//
#include <hip/hip_runtime.h>
#include <math.h>

#define BB 16
#define KK 4
#define VV 32000
#define DD 512
#define LL 32
#define EOS_ID 2
#define NEGINF 1.0e7f
#define ALPHA_C 0.6f
#define NROW (BB * KK)        // 64
#define NCHUNK 4
#define CHSZ (VV / NCHUNK)    // 8000
#define SPLIT_S 2048.0f

typedef _Float16 f16x8 __attribute__((ext_vector_type(8)));
typedef float f32x4 __attribute__((ext_vector_type(4)));

// pack h value (global row r, depth d) into MFMA A-fragment order (fp16 hi/lo split)
// frag layout for mfma_f32_16x16x32_f16: lane l -> row=l&15, k = (l>>4)*8 + j
__device__ inline void pack_h(int r, int d, float v,
                              _Float16* __restrict__ hfrag_hi,
                              _Float16* __restrict__ hfrag_lo) {
    _Float16 hi = (_Float16)v;
    _Float16 lo = (_Float16)((v - (float)hi) * SPLIT_S);
    int rg = r >> 4;
    int ks = d >> 5;
    int lane = (r & 15) + 16 * ((d >> 3) & 3);
    int e = d & 7;
    int off = (((rg * 16 + ks) * 64) + lane) * 8 + e;
    hfrag_hi[off] = hi;
    hfrag_lo[off] = lo;
}

// ---------------- init: sequences / scores ----------------
__global__ void k_init(const int* __restrict__ initial_ids,
                       int* alive_seq, float* alive_lp,
                       int* fin_seq, float* fin_sc, int* fin_fl) {
    int tid = blockIdx.x * blockDim.x + threadIdx.x;
    int nthreads = gridDim.x * blockDim.x;
    const int SEQ = NROW * (LL + 1);
    for (int idx = tid; idx < SEQ; idx += nthreads) {
        int pos = idx % (LL + 1);
        int b = (idx / (LL + 1)) / KK;
        alive_seq[idx] = (pos == 0) ? initial_ids[b] : 0;
        fin_seq[idx] = 0;
    }
    for (int idx = tid; idx < NROW; idx += nthreads) {
        int k = idx % KK;
        alive_lp[idx] = (k == 0) ? 0.0f : -NEGINF;
        fin_sc[idx] = -NEGINF;
        fin_fl[idx] = 0;
    }
}

// ---------------- initial h ----------------
__global__ void k_hinit(const int* __restrict__ initial_ids,
                        const float* __restrict__ init_h,
                        const float* __restrict__ embed,
                        float* __restrict__ h_buf,
                        _Float16* __restrict__ hfrag_hi,
                        _Float16* __restrict__ hfrag_lo) {
    int row = blockIdx.x;
    int b = row >> 2;
    int t = threadIdx.x;
    int tok = initial_ids[b];
    for (int d = t; d < DD; d += 256) {
        float v = tanhf(init_h[b * DD + d] + embed[(size_t)tok * DD + d]);
        h_buf[row * DD + d] = v;
        pack_h(row, d, v, hfrag_hi, hfrag_lo);
    }
}

// ---------------- logits via MFMA fp16x2 split ----------------
// grid 500, block 256 (4 waves). Wave w: col-tile ct = blockIdx*4+w (16 cols), all 64 rows.
// acc1 = hi*hi ; acc2 = hi*lo + lo*hi ; logit = acc1 + acc2/2048.
__global__ __launch_bounds__(256) void k_logits(
        const float* __restrict__ proj,
        const _Float16* __restrict__ hfrag_hi,
        const _Float16* __restrict__ hfrag_lo,
        float* __restrict__ logits) {
    int t = threadIdx.x;
    int w = t >> 6, l = t & 63;
    int ct = blockIdx.x * 4 + w;
    int c0 = ct * 16;
    int colr = l & 15;
    int kg = l >> 4;

    f32x4 acc1[4], acc2[4];
    #pragma unroll
    for (int rg = 0; rg < 4; rg++) {
        acc1[rg] = (f32x4){0.f, 0.f, 0.f, 0.f};
        acc2[rg] = (f32x4){0.f, 0.f, 0.f, 0.f};
    }

    for (int ks = 0; ks < 16; ks++) {
        int k0 = ks * 32 + kg * 8;
        const float* bp = proj + (size_t)k0 * VV + c0 + colr;
        f16x8 bh, bl;
        #pragma unroll
        for (int j = 0; j < 8; j++) {
            float v = bp[(size_t)j * VV];
            _Float16 hi = (_Float16)v;
            bh[j] = hi;
            bl[j] = (_Float16)((v - (float)hi) * SPLIT_S);
        }
        #pragma unroll
        for (int rg = 0; rg < 4; rg++) {
            int off = ((rg * 16 + ks) * 64 + l) * 8;
            f16x8 ah = *reinterpret_cast<const f16x8*>(hfrag_hi + off);
            f16x8 al = *reinterpret_cast<const f16x8*>(hfrag_lo + off);
            acc1[rg] = __builtin_amdgcn_mfma_f32_16x16x32_f16(ah, bh, acc1[rg], 0, 0, 0);
            acc2[rg] = __builtin_amdgcn_mfma_f32_16x16x32_f16(ah, bl, acc2[rg], 0, 0, 0);
            acc2[rg] = __builtin_amdgcn_mfma_f32_16x16x32_f16(al, bh, acc2[rg], 0, 0, 0);
        }
    }
    // C layout: col = lane&15, row = (lane>>4)*4 + reg (m89, dtype-independent)
    #pragma unroll
    for (int rg = 0; rg < 4; rg++) {
        #pragma unroll
        for (int j = 0; j < 4; j++) {
            int row = rg * 16 + kg * 4 + j;
            logits[(size_t)row * VV + c0 + colr] =
                acc1[rg][j] + acc2[rg][j] * (1.0f / SPLIT_S);
        }
    }
}

// ---------------- per (row, col-chunk): stable top-8 + online max/expsum, ONE pass ----------------
// grid (NCHUNK, NROW), block 256
__global__ __launch_bounds__(256) void k_rowpart(
        const float* __restrict__ logits,
        float* __restrict__ ptop_val, int* __restrict__ ptop_idx,
        float* __restrict__ pmax, float* __restrict__ psum) {
    int chunk = blockIdx.x;
    int row = blockIdx.y;
    int t = threadIdx.x;
    const float* lg = logits + (size_t)row * VV;
    int cbeg = chunk * CHSZ, cend = cbeg + CHSZ;

    float lv[8]; int li[8];
    #pragma unroll
    for (int j = 0; j < 8; j++) { lv[j] = -INFINITY; li[j] = 0x7fffffff; }
    float m = -INFINITY, s = 0.0f;
    for (int c = cbeg + t; c < cend; c += 256) {
        float v = lg[c];
        if (v > m) { s = s * expf(m - v) + 1.0f; m = v; }
        else       { s += expf(v - m); }
        if (v > lv[7]) {
            int j = 7;
            while (j > 0 && v > lv[j - 1]) { lv[j] = lv[j - 1]; li[j] = li[j - 1]; j--; }
            lv[j] = v; li[j] = c;   // strict >: equal values keep earlier index first
        }
    }
    __shared__ float sval[256][8];
    __shared__ int   sidx[256][8];
    __shared__ float sm[256], ss[256];
    #pragma unroll
    for (int j = 0; j < 8; j++) { sval[t][j] = lv[j]; sidx[t][j] = li[j]; }
    sm[t] = m; ss[t] = s;
    __syncthreads();
    for (int st = 128; st > 0; st >>= 1) {
        if (t < st) {
            float rv[8]; int ri[8];
            int pa = 0, pb = 0;
            #pragma unroll
            for (int j = 0; j < 8; j++) {
                bool aok = pa < 8, bok = pb < 8;
                float va = sval[t][aok ? pa : 7],     vb = sval[t + st][bok ? pb : 7];
                int   ia = sidx[t][aok ? pa : 7],     ib = sidx[t + st][bok ? pb : 7];
                bool takeA = !bok || (aok && ((va > vb) || (va == vb && ia <= ib)));
                if (takeA) { rv[j] = va; ri[j] = ia; pa++; }
                else       { rv[j] = vb; ri[j] = ib; pb++; }
            }
            #pragma unroll
            for (int j = 0; j < 8; j++) { sval[t][j] = rv[j]; sidx[t][j] = ri[j]; }
            float ma = sm[t], mb = sm[t + st];
            float M = fmaxf(ma, mb);
            ss[t] = ss[t] * expf(ma - M) + ss[t + st] * expf(mb - M);
            sm[t] = M;
        }
        __syncthreads();
    }
    if (t == 0) {
        #pragma unroll
        for (int j = 0; j < 8; j++) {
            ptop_val[(row * NCHUNK + chunk) * 8 + j] = sval[0][j];
            ptop_idx[(row * NCHUNK + chunk) * 8 + j] = sidx[0][j];
        }
        pmax[row * NCHUNK + chunk] = sm[0];
        psum[row * NCHUNK + chunk] = ss[0];
    }
}

// ---------------- beam update: fully parallel rank-based selection ----------------
// grid BB, block 256
__global__ __launch_bounds__(256) void k_update(
        const float* __restrict__ embed,
        float* h_buf, int* alive_seq, float* alive_lp,
        int* fin_seq, float* fin_sc, int* fin_fl,
        const float* __restrict__ ptop_val, const int* __restrict__ ptop_idx,
        const float* __restrict__ pmax, const float* __restrict__ psum,
        _Float16* __restrict__ hfrag_hi, _Float16* __restrict__ hfrag_lo,
        int step) {
    int b = blockIdx.x;
    int t = threadIdx.x;
    __shared__ float h_old[KK][DD];
    __shared__ int old_aseq[KK][LL + 1], old_fseq[KK][LL + 1];
    __shared__ float lse_s[KK], alp_s[KK];
    __shared__ float clp[128]; __shared__ int cidx[128];
    __shared__ float c_lp[8];  __shared__ int c_beam[8], c_id[8], c_fl[8];
    __shared__ float asc_s[8], comb_s[12]; __shared__ int combfl_s[12];
    __shared__ int sel_alive[KK], sel_fin[KK];
    __shared__ float n_alp[KK], n_fsc[KK]; __shared__ int n_ffl[KK];

    for (int idx = t; idx < KK * (LL + 1); idx += 256) {
        old_aseq[idx / (LL + 1)][idx % (LL + 1)] = alive_seq[b * KK * (LL + 1) + idx];
        old_fseq[idx / (LL + 1)][idx % (LL + 1)] = fin_seq[b * KK * (LL + 1) + idx];
    }
    for (int idx = t; idx < KK * DD; idx += 256)
        h_old[idx >> 9][idx & (DD - 1)] = h_buf[b * KK * DD + idx];
    if (t < KK) {
        int r = b * KK + t;
        float m = fmaxf(fmaxf(pmax[r * 4 + 0], pmax[r * 4 + 1]),
                        fmaxf(pmax[r * 4 + 2], pmax[r * 4 + 3]));
        float s = 0.0f;
        #pragma unroll
        for (int c2 = 0; c2 < 4; c2++) s += psum[r * 4 + c2] * expf(pmax[r * 4 + c2] - m);
        lse_s[t] = m + logf(s);
        alp_s[t] = alive_lp[r];
    }
    __syncthreads();

    // 128 candidates = 4 rows x 4 chunks x 8. lp = logit - lse + alive_lp.
    if (t < 128) {
        int row = t >> 5;
        int src = ((b * KK + row) * NCHUNK + ((t >> 3) & 3)) * 8 + (t & 7);
        clp[t] = ptop_val[src] - lse_s[row] + alp_s[row];
        cidx[t] = ptop_idx[src];
    }
    __syncthreads();
    // stable rank over all 128 (tie key = row*V + token, ascending) -> top-8
    if (t < 128) {
        int row = t >> 5;
        float mylp = clp[t];
        int mykey = row * VV + cidx[t];
        int cnt = 0;
        for (int j = 0; j < 128; j++) {
            float lj = clp[j];
            int kj = (j >> 5) * VV + cidx[j];
            cnt += (lj > mylp) || (lj == mylp && kj < mykey);
        }
        if (cnt < 8) {
            c_lp[cnt] = mylp; c_beam[cnt] = row; c_id[cnt] = cidx[t];
            c_fl[cnt] = (cidx[t] == EOS_ID) ? 1 : 0;
        }
    }
    __syncthreads();
    if (t < 8) asc_s[t] = c_lp[t] + (c_fl[t] ? -NEGINF : 0.0f);
    if (t >= 64 && t < 76) {
        int j2 = t - 64;
        if (j2 < 4) { comb_s[j2] = fin_sc[b * KK + j2]; combfl_s[j2] = fin_fl[b * KK + j2]; }
        else {
            int cc = j2 - 4;
            float ln = powf((6.0f + (float)step) / 6.0f, ALPHA_C);
            comb_s[j2] = c_lp[cc] / ln + (c_fl[cc] ? 0.0f : -NEGINF);
            combfl_s[j2] = c_fl[cc];
        }
    }
    __syncthreads();
    if (t < 8) {   // alive: stable top-4 of asc (ties: lower position)
        float a = asc_s[t];
        int cnt = 0;
        #pragma unroll
        for (int j = 0; j < 8; j++) cnt += (asc_s[j] > a) || (asc_s[j] == a && j < t);
        if (cnt < KK) { sel_alive[cnt] = t; n_alp[cnt] = a; }
    }
    if (t >= 64 && t < 76) {  // finished: stable top-4 of comb (ties: lower position)
        int j2 = t - 64;
        float cval = comb_s[j2];
        int cnt = 0;
        #pragma unroll
        for (int j = 0; j < 12; j++) cnt += (comb_s[j] > cval) || (comb_s[j] == cval && j < j2);
        if (cnt < KK) { sel_fin[cnt] = j2; n_fsc[cnt] = cval; n_ffl[cnt] = combfl_s[j2]; }
    }
    __syncthreads();

    // write new sequences
    for (int idx = t; idx < KK * (LL + 1); idx += 256) {
        int j = idx / (LL + 1), p = idx % (LL + 1);
        int cand = sel_alive[j], bm = c_beam[cand];
        alive_seq[b * KK * (LL + 1) + idx] = (p == step + 1) ? c_id[cand] : old_aseq[bm][p];
        int src = sel_fin[j];
        int fval;
        if (src < 4) fval = old_fseq[src][p];
        else {
            int c2 = src - 4, bm2 = c_beam[c2];
            fval = (p == step + 1) ? c_id[c2] : old_aseq[bm2][p];
        }
        fin_seq[b * KK * (LL + 1) + idx] = fval;
    }
    // next-step h: h' = tanh(h_old[selected beam] + embed[new token]); also pack fp16 frags
    for (int idx = t; idx < KK * DD; idx += 256) {
        int j = idx >> 9, d = idx & (DD - 1);
        int cand = sel_alive[j], bm = c_beam[cand], tok = c_id[cand];
        float v = tanhf(h_old[bm][d] + embed[(size_t)tok * DD + d]);
        int r = b * KK + j;
        h_buf[(size_t)r * DD + d] = v;
        pack_h(r, d, v, hfrag_hi, hfrag_lo);
    }
    if (t < KK) {
        alive_lp[b * KK + t] = n_alp[t];
        fin_sc[b * KK + t] = n_fsc[t];
        fin_fl[b * KK + t] = n_ffl[t];
    }
}

// ---------------- finalize ----------------
__global__ void k_final(const int* __restrict__ alive_seq, const float* __restrict__ alive_lp,
                        const int* __restrict__ fin_seq, const float* __restrict__ fin_sc,
                        const int* __restrict__ fin_fl, float* __restrict__ out) {
    int b = blockIdx.x;
    int t = threadIdx.x;
    __shared__ int anyf;
    if (t == 0)
        anyf = fin_fl[b * KK] | fin_fl[b * KK + 1] | fin_fl[b * KK + 2] | fin_fl[b * KK + 3];
    __syncthreads();
    for (int idx = t; idx < KK * (LL + 1); idx += blockDim.x) {
        int src = anyf ? fin_seq[b * KK * (LL + 1) + idx] : alive_seq[b * KK * (LL + 1) + idx];
        out[b * KK * (LL + 1) + idx] = (float)src;
    }
    if (t < KK)
        out[BB * KK * (LL + 1) + b * KK + t] = anyf ? fin_sc[b * KK + t] : alive_lp[b * KK + t];
}

extern "C" void kernel_launch(void* const* d_in, const int* in_sizes, int n_in,
                              void* d_out, int out_size, void* d_ws, size_t ws_size,
                              hipStream_t stream) {
    const int* initial_ids = (const int*)d_in[0];
    const float* init_h = (const float*)d_in[1];
    const float* embed = (const float*)d_in[2];
    const float* proj = (const float*)d_in[3];
    float* out = (float*)d_out;

    char* ws = (char*)d_ws;
    size_t off = 0;
    auto alloc = [&](size_t bytes) -> void* {
        off = (off + 255) & ~(size_t)255;
        void* p = ws + off;
        off += bytes;
        return p;
    };
    int* alive_seq    = (int*)alloc((size_t)NROW * (LL + 1) * 4);
    int* fin_seq      = (int*)alloc((size_t)NROW * (LL + 1) * 4);
    float* alive_lp   = (float*)alloc((size_t)NROW * 4);
    float* fin_sc     = (float*)alloc((size_t)NROW * 4);
    int* fin_fl       = (int*)alloc((size_t)NROW * 4);
    float* h_buf      = (float*)alloc((size_t)NROW * DD * 4);
    float* logits     = (float*)alloc((size_t)NROW * VV * 4);
    float* ptop_val   = (float*)alloc((size_t)NROW * NCHUNK * 8 * 4);
    int* ptop_idx     = (int*)alloc((size_t)NROW * NCHUNK * 8 * 4);
    float* pmax       = (float*)alloc((size_t)NROW * NCHUNK * 4);
    float* psum       = (float*)alloc((size_t)NROW * NCHUNK * 4);
    _Float16* hfrag_hi = (_Float16*)alloc((size_t)NROW * DD * 2);
    _Float16* hfrag_lo = (_Float16*)alloc((size_t)NROW * DD * 2);

    k_init<<<16, 256, 0, stream>>>(initial_ids, alive_seq, alive_lp,
                                   fin_seq, fin_sc, fin_fl);
    k_hinit<<<NROW, 256, 0, stream>>>(initial_ids, init_h, embed, h_buf,
                                      hfrag_hi, hfrag_lo);
    for (int step = 0; step < LL; step++) {
        k_logits<<<500, 256, 0, stream>>>(proj, hfrag_hi, hfrag_lo, logits);
        k_rowpart<<<dim3(NCHUNK, NROW), 256, 0, stream>>>(logits, ptop_val, ptop_idx,
                                                          pmax, psum);
        k_update<<<BB, 256, 0, stream>>>(embed, h_buf, alive_seq, alive_lp,
                                         fin_seq, fin_sc, fin_fl,
                                         ptop_val, ptop_idx, pmax, psum,
                                         hfrag_hi, hfrag_lo, step);
    }
    k_final<<<BB, 64, 0, stream>>>(alive_seq, alive_lp, fin_seq, fin_sc, fin_fl, out);
}

// Round 4
// 1859.598 us; speedup vs baseline: 4.8313x; 1.1359x over previous
//
#include <hip/hip_runtime.h>
#include <math.h>

#define BB 16
#define KK 4
#define VV 32000
#define DD 512
#define LL 32
#define EOS_ID 2
#define NEGINF 1.0e7f
#define ALPHA_C 0.6f
#define NROW (BB * KK)        // 64
#define NCHUNK 8
#define CHSZ (VV / NCHUNK)    // 4000
#define SPLIT_S 2048.0f

typedef _Float16 f16x8 __attribute__((ext_vector_type(8)));
typedef float f32x4 __attribute__((ext_vector_type(4)));

// pack h value (global row r, depth d) into MFMA A-fragment order (fp16 hi/lo split)
// frag layout for mfma_f32_16x16x32_f16: lane l -> row=l&15, k = (l>>4)*8 + j
__device__ inline void pack_h(int r, int d, float v,
                              _Float16* __restrict__ hfrag_hi,
                              _Float16* __restrict__ hfrag_lo) {
    _Float16 hi = (_Float16)v;
    _Float16 lo = (_Float16)((v - (float)hi) * SPLIT_S);
    int rg = r >> 4;
    int ks = d >> 5;
    int lane = (r & 15) + 16 * ((d >> 3) & 3);
    int e = d & 7;
    int off = (((rg * 16 + ks) * 64) + lane) * 8 + e;
    hfrag_hi[off] = hi;
    hfrag_lo[off] = lo;
}

// ---------------- init: sequences / scores ----------------
__global__ void k_init(const int* __restrict__ initial_ids,
                       int* alive_seq, float* alive_lp,
                       int* fin_seq, float* fin_sc, int* fin_fl) {
    int tid = blockIdx.x * blockDim.x + threadIdx.x;
    int nthreads = gridDim.x * blockDim.x;
    const int SEQ = NROW * (LL + 1);
    for (int idx = tid; idx < SEQ; idx += nthreads) {
        int pos = idx % (LL + 1);
        int b = (idx / (LL + 1)) / KK;
        alive_seq[idx] = (pos == 0) ? initial_ids[b] : 0;
        fin_seq[idx] = 0;
    }
    for (int idx = tid; idx < NROW; idx += nthreads) {
        int k = idx % KK;
        alive_lp[idx] = (k == 0) ? 0.0f : -NEGINF;
        fin_sc[idx] = -NEGINF;
        fin_fl[idx] = 0;
    }
}

// ---------------- one-time: proj -> fp16 hi/lo B-fragments (fragment-ordered) ----------
// grid 2000 (one per col-tile ct), block 256 (4 waves; wave w does ks = w,w+4,w+8,w+12)
__global__ __launch_bounds__(256) void k_bconv(const float* __restrict__ proj,
                                               _Float16* __restrict__ bfrag_hi,
                                               _Float16* __restrict__ bfrag_lo) {
    int ct = blockIdx.x;
    int t = threadIdx.x;
    int w = t >> 6, l = t & 63;
    int col = ct * 16 + (l & 15);
    int kg = l >> 4;
    for (int ks = w; ks < 16; ks += 4) {
        int k0 = ks * 32 + kg * 8;
        f16x8 hi, lo;
        #pragma unroll
        for (int j = 0; j < 8; j++) {
            float v = proj[(size_t)(k0 + j) * VV + col];
            _Float16 h = (_Float16)v;
            hi[j] = h;
            lo[j] = (_Float16)((v - (float)h) * SPLIT_S);
        }
        size_t off = (size_t)(ct * 16 + ks) * 64 + l;
        reinterpret_cast<f16x8*>(bfrag_hi)[off] = hi;
        reinterpret_cast<f16x8*>(bfrag_lo)[off] = lo;
    }
}

// ---------------- initial h ----------------
__global__ void k_hinit(const int* __restrict__ initial_ids,
                        const float* __restrict__ init_h,
                        const float* __restrict__ embed,
                        float* __restrict__ h_buf,
                        _Float16* __restrict__ hfrag_hi,
                        _Float16* __restrict__ hfrag_lo) {
    int row = blockIdx.x;
    int b = row >> 2;
    int t = threadIdx.x;
    int tok = initial_ids[b];
    for (int d = t; d < DD; d += 256) {
        float v = tanhf(init_h[b * DD + d] + embed[(size_t)tok * DD + d]);
        h_buf[row * DD + d] = v;
        pack_h(row, d, v, hfrag_hi, hfrag_lo);
    }
}

// ---------------- logits via MFMA fp16x2 split, pre-converted B ----------------
// grid 500, block 256 (4 waves). Wave w: col-tile ct = blockIdx*4+w (16 cols), all 64 rows.
// acc1 = hi*hi ; acc2 = hi*lo + lo*hi ; logit = acc1 + acc2/2048.
__global__ __launch_bounds__(256) void k_logits(
        const _Float16* __restrict__ bfrag_hi,
        const _Float16* __restrict__ bfrag_lo,
        const _Float16* __restrict__ hfrag_hi,
        const _Float16* __restrict__ hfrag_lo,
        float* __restrict__ logits) {
    int t = threadIdx.x;
    int w = t >> 6, l = t & 63;
    int ct = blockIdx.x * 4 + w;
    int c0 = ct * 16;
    int colr = l & 15;
    int kg = l >> 4;

    const f16x8* Bh = reinterpret_cast<const f16x8*>(bfrag_hi) + (size_t)ct * 16 * 64 + l;
    const f16x8* Bl = reinterpret_cast<const f16x8*>(bfrag_lo) + (size_t)ct * 16 * 64 + l;
    const f16x8* Ah = reinterpret_cast<const f16x8*>(hfrag_hi) + l;
    const f16x8* Al = reinterpret_cast<const f16x8*>(hfrag_lo) + l;

    f32x4 acc1[4], acc2[4];
    #pragma unroll
    for (int rg = 0; rg < 4; rg++) {
        acc1[rg] = (f32x4){0.f, 0.f, 0.f, 0.f};
        acc2[rg] = (f32x4){0.f, 0.f, 0.f, 0.f};
    }

    f16x8 bh = Bh[0], bl = Bl[0];
    f16x8 ah0 = Ah[0],    al0 = Al[0];
    f16x8 ah1 = Ah[1024], al1 = Al[1024];
    f16x8 ah2 = Ah[2048], al2 = Al[2048];
    f16x8 ah3 = Ah[3072], al3 = Al[3072];

    for (int ks = 0; ks < 16; ks++) {
        f16x8 nbh, nbl, nah0, nal0, nah1, nal1, nah2, nal2, nah3, nal3;
        if (ks < 15) {
            int nx = (ks + 1) * 64;
            nbh = Bh[nx];            nbl = Bl[nx];
            nah0 = Ah[nx];           nal0 = Al[nx];
            nah1 = Ah[1024 + nx];    nal1 = Al[1024 + nx];
            nah2 = Ah[2048 + nx];    nal2 = Al[2048 + nx];
            nah3 = Ah[3072 + nx];    nal3 = Al[3072 + nx];
        }
        acc1[0] = __builtin_amdgcn_mfma_f32_16x16x32_f16(ah0, bh, acc1[0], 0, 0, 0);
        acc2[0] = __builtin_amdgcn_mfma_f32_16x16x32_f16(ah0, bl, acc2[0], 0, 0, 0);
        acc2[0] = __builtin_amdgcn_mfma_f32_16x16x32_f16(al0, bh, acc2[0], 0, 0, 0);
        acc1[1] = __builtin_amdgcn_mfma_f32_16x16x32_f16(ah1, bh, acc1[1], 0, 0, 0);
        acc2[1] = __builtin_amdgcn_mfma_f32_16x16x32_f16(ah1, bl, acc2[1], 0, 0, 0);
        acc2[1] = __builtin_amdgcn_mfma_f32_16x16x32_f16(al1, bh, acc2[1], 0, 0, 0);
        acc1[2] = __builtin_amdgcn_mfma_f32_16x16x32_f16(ah2, bh, acc1[2], 0, 0, 0);
        acc2[2] = __builtin_amdgcn_mfma_f32_16x16x32_f16(ah2, bl, acc2[2], 0, 0, 0);
        acc2[2] = __builtin_amdgcn_mfma_f32_16x16x32_f16(al2, bh, acc2[2], 0, 0, 0);
        acc1[3] = __builtin_amdgcn_mfma_f32_16x16x32_f16(ah3, bh, acc1[3], 0, 0, 0);
        acc2[3] = __builtin_amdgcn_mfma_f32_16x16x32_f16(ah3, bl, acc2[3], 0, 0, 0);
        acc2[3] = __builtin_amdgcn_mfma_f32_16x16x32_f16(al3, bh, acc2[3], 0, 0, 0);
        if (ks < 15) {
            bh = nbh; bl = nbl;
            ah0 = nah0; al0 = nal0;
            ah1 = nah1; al1 = nal1;
            ah2 = nah2; al2 = nal2;
            ah3 = nah3; al3 = nal3;
        }
    }
    // C layout: col = lane&15, row = (lane>>4)*4 + reg (dtype-independent)
    #pragma unroll
    for (int rg = 0; rg < 4; rg++) {
        #pragma unroll
        for (int j = 0; j < 4; j++) {
            int row = rg * 16 + kg * 4 + j;
            logits[(size_t)row * VV + c0 + colr] =
                acc1[rg][j] + acc2[rg][j] * (1.0f / SPLIT_S);
        }
    }
}

// ---------------- per (row, col-chunk): stable top-8 + online max/expsum, ONE pass ----------------
// grid (NCHUNK, NROW), block 256
__global__ __launch_bounds__(256) void k_rowpart(
        const float* __restrict__ logits,
        float* __restrict__ ptop_val, int* __restrict__ ptop_idx,
        float* __restrict__ pmax, float* __restrict__ psum) {
    int chunk = blockIdx.x;
    int row = blockIdx.y;
    int t = threadIdx.x;
    int cbeg = chunk * CHSZ;
    const float4* lg4 = reinterpret_cast<const float4*>(logits + (size_t)row * VV + cbeg);

    float lv[8]; int li[8];
    #pragma unroll
    for (int j = 0; j < 8; j++) { lv[j] = -INFINITY; li[j] = 0x7fffffff; }
    float m = -INFINITY, s = 0.0f;
    for (int i = t; i < CHSZ / 4; i += 256) {
        float4 v4 = lg4[i];
        #pragma unroll
        for (int j2 = 0; j2 < 4; j2++) {
            float v = (j2 == 0) ? v4.x : (j2 == 1) ? v4.y : (j2 == 2) ? v4.z : v4.w;
            if (v > m) { s = s * expf(m - v) + 1.0f; m = v; }
            else       { s += expf(v - m); }
            if (v > lv[7]) {
                int c = cbeg + i * 4 + j2;
                int j = 7;
                while (j > 0 && v > lv[j - 1]) { lv[j] = lv[j - 1]; li[j] = li[j - 1]; j--; }
                lv[j] = v; li[j] = c;   // strict >: equal values keep earlier index first
            }
        }
    }
    __shared__ float sval[256][8];
    __shared__ int   sidx[256][8];
    __shared__ float sm[256], ss[256];
    #pragma unroll
    for (int j = 0; j < 8; j++) { sval[t][j] = lv[j]; sidx[t][j] = li[j]; }
    sm[t] = m; ss[t] = s;
    __syncthreads();
    for (int st = 128; st > 0; st >>= 1) {
        if (t < st) {
            float rv[8]; int ri[8];
            int pa = 0, pb = 0;
            #pragma unroll
            for (int j = 0; j < 8; j++) {
                bool aok = pa < 8, bok = pb < 8;
                float va = sval[t][aok ? pa : 7],     vb = sval[t + st][bok ? pb : 7];
                int   ia = sidx[t][aok ? pa : 7],     ib = sidx[t + st][bok ? pb : 7];
                bool takeA = !bok || (aok && ((va > vb) || (va == vb && ia <= ib)));
                if (takeA) { rv[j] = va; ri[j] = ia; pa++; }
                else       { rv[j] = vb; ri[j] = ib; pb++; }
            }
            #pragma unroll
            for (int j = 0; j < 8; j++) { sval[t][j] = rv[j]; sidx[t][j] = ri[j]; }
            float ma = sm[t], mb = sm[t + st];
            float M = fmaxf(ma, mb);
            ss[t] = ss[t] * expf(ma - M) + ss[t + st] * expf(mb - M);
            sm[t] = M;
        }
        __syncthreads();
    }
    if (t == 0) {
        #pragma unroll
        for (int j = 0; j < 8; j++) {
            ptop_val[(row * NCHUNK + chunk) * 8 + j] = sval[0][j];
            ptop_idx[(row * NCHUNK + chunk) * 8 + j] = sidx[0][j];
        }
        pmax[row * NCHUNK + chunk] = sm[0];
        psum[row * NCHUNK + chunk] = ss[0];
    }
}

// ---------------- beam update: fully parallel rank-based selection ----------------
// grid BB, block 256
__global__ __launch_bounds__(256) void k_update(
        const float* __restrict__ embed,
        float* h_buf, int* alive_seq, float* alive_lp,
        int* fin_seq, float* fin_sc, int* fin_fl,
        const float* __restrict__ ptop_val, const int* __restrict__ ptop_idx,
        const float* __restrict__ pmax, const float* __restrict__ psum,
        _Float16* __restrict__ hfrag_hi, _Float16* __restrict__ hfrag_lo,
        int step) {
    int b = blockIdx.x;
    int t = threadIdx.x;
    __shared__ float h_old[KK][DD];
    __shared__ int old_aseq[KK][LL + 1], old_fseq[KK][LL + 1];
    __shared__ float lse_s[KK], alp_s[KK];
    __shared__ float clp[256]; __shared__ int cidx[256];
    __shared__ float c_lp[8];  __shared__ int c_beam[8], c_id[8], c_fl[8];
    __shared__ float asc_s[8], comb_s[12]; __shared__ int combfl_s[12];
    __shared__ int sel_alive[KK], sel_fin[KK];
    __shared__ float n_alp[KK], n_fsc[KK]; __shared__ int n_ffl[KK];

    for (int idx = t; idx < KK * (LL + 1); idx += 256) {
        old_aseq[idx / (LL + 1)][idx % (LL + 1)] = alive_seq[b * KK * (LL + 1) + idx];
        old_fseq[idx / (LL + 1)][idx % (LL + 1)] = fin_seq[b * KK * (LL + 1) + idx];
    }
    for (int idx = t; idx < KK * DD; idx += 256)
        h_old[idx >> 9][idx & (DD - 1)] = h_buf[b * KK * DD + idx];
    if (t < KK) {
        int r = b * KK + t;
        float m = -INFINITY;
        #pragma unroll
        for (int c2 = 0; c2 < NCHUNK; c2++) m = fmaxf(m, pmax[r * NCHUNK + c2]);
        float s = 0.0f;
        #pragma unroll
        for (int c2 = 0; c2 < NCHUNK; c2++)
            s += psum[r * NCHUNK + c2] * expf(pmax[r * NCHUNK + c2] - m);
        lse_s[t] = m + logf(s);
        alp_s[t] = alive_lp[r];
    }
    __syncthreads();

    // 256 candidates = 4 rows x 8 chunks x 8. lp = logit - lse + alive_lp.
    {
        int row = t >> 6;
        int src = ((b * KK + row) * NCHUNK + ((t >> 3) & 7)) * 8 + (t & 7);
        clp[t] = ptop_val[src] - lse_s[row] + alp_s[row];
        cidx[t] = ptop_idx[src];
    }
    __syncthreads();
    // stable rank over all 256 (tie key = row*V + token, ascending) -> top-8
    {
        int row = t >> 6;
        float mylp = clp[t];
        int mykey = row * VV + cidx[t];
        int cnt = 0;
        for (int j = 0; j < 256; j++) {
            float lj = clp[j];
            int kj = (j >> 6) * VV + cidx[j];
            cnt += (lj > mylp) || (lj == mylp && kj < mykey);
        }
        if (cnt < 8) {
            c_lp[cnt] = mylp; c_beam[cnt] = row; c_id[cnt] = cidx[t];
            c_fl[cnt] = (cidx[t] == EOS_ID) ? 1 : 0;
        }
    }
    __syncthreads();
    if (t < 8) asc_s[t] = c_lp[t] + (c_fl[t] ? -NEGINF : 0.0f);
    if (t >= 64 && t < 76) {
        int j2 = t - 64;
        if (j2 < 4) { comb_s[j2] = fin_sc[b * KK + j2]; combfl_s[j2] = fin_fl[b * KK + j2]; }
        else {
            int cc = j2 - 4;
            float ln = powf((6.0f + (float)step) / 6.0f, ALPHA_C);
            comb_s[j2] = c_lp[cc] / ln + (c_fl[cc] ? 0.0f : -NEGINF);
            combfl_s[j2] = c_fl[cc];
        }
    }
    __syncthreads();
    if (t < 8) {   // alive: stable top-4 of asc (ties: lower position)
        float a = asc_s[t];
        int cnt = 0;
        #pragma unroll
        for (int j = 0; j < 8; j++) cnt += (asc_s[j] > a) || (asc_s[j] == a && j < t);
        if (cnt < KK) { sel_alive[cnt] = t; n_alp[cnt] = a; }
    }
    if (t >= 64 && t < 76) {  // finished: stable top-4 of comb (ties: lower position)
        int j2 = t - 64;
        float cval = comb_s[j2];
        int cnt = 0;
        #pragma unroll
        for (int j = 0; j < 12; j++) cnt += (comb_s[j] > cval) || (comb_s[j] == cval && j < j2);
        if (cnt < KK) { sel_fin[cnt] = j2; n_fsc[cnt] = cval; n_ffl[cnt] = combfl_s[j2]; }
    }
    __syncthreads();

    // write new sequences
    for (int idx = t; idx < KK * (LL + 1); idx += 256) {
        int j = idx / (LL + 1), p = idx % (LL + 1);
        int cand = sel_alive[j], bm = c_beam[cand];
        alive_seq[b * KK * (LL + 1) + idx] = (p == step + 1) ? c_id[cand] : old_aseq[bm][p];
        int src = sel_fin[j];
        int fval;
        if (src < 4) fval = old_fseq[src][p];
        else {
            int c2 = src - 4, bm2 = c_beam[c2];
            fval = (p == step + 1) ? c_id[c2] : old_aseq[bm2][p];
        }
        fin_seq[b * KK * (LL + 1) + idx] = fval;
    }
    // next-step h: h' = tanh(h_old[selected beam] + embed[new token]); also pack fp16 frags
    for (int idx = t; idx < KK * DD; idx += 256) {
        int j = idx >> 9, d = idx & (DD - 1);
        int cand = sel_alive[j], bm = c_beam[cand], tok = c_id[cand];
        float v = tanhf(h_old[bm][d] + embed[(size_t)tok * DD + d]);
        int r = b * KK + j;
        h_buf[(size_t)r * DD + d] = v;
        pack_h(r, d, v, hfrag_hi, hfrag_lo);
    }
    if (t < KK) {
        alive_lp[b * KK + t] = n_alp[t];
        fin_sc[b * KK + t] = n_fsc[t];
        fin_fl[b * KK + t] = n_ffl[t];
    }
}

// ---------------- finalize ----------------
__global__ void k_final(const int* __restrict__ alive_seq, const float* __restrict__ alive_lp,
                        const int* __restrict__ fin_seq, const float* __restrict__ fin_sc,
                        const int* __restrict__ fin_fl, float* __restrict__ out) {
    int b = blockIdx.x;
    int t = threadIdx.x;
    __shared__ int anyf;
    if (t == 0)
        anyf = fin_fl[b * KK] | fin_fl[b * KK + 1] | fin_fl[b * KK + 2] | fin_fl[b * KK + 3];
    __syncthreads();
    for (int idx = t; idx < KK * (LL + 1); idx += blockDim.x) {
        int src = anyf ? fin_seq[b * KK * (LL + 1) + idx] : alive_seq[b * KK * (LL + 1) + idx];
        out[b * KK * (LL + 1) + idx] = (float)src;
    }
    if (t < KK)
        out[BB * KK * (LL + 1) + b * KK + t] = anyf ? fin_sc[b * KK + t] : alive_lp[b * KK + t];
}

extern "C" void kernel_launch(void* const* d_in, const int* in_sizes, int n_in,
                              void* d_out, int out_size, void* d_ws, size_t ws_size,
                              hipStream_t stream) {
    const int* initial_ids = (const int*)d_in[0];
    const float* init_h = (const float*)d_in[1];
    const float* embed = (const float*)d_in[2];
    const float* proj = (const float*)d_in[3];
    float* out = (float*)d_out;

    char* ws = (char*)d_ws;
    size_t off = 0;
    auto alloc = [&](size_t bytes) -> void* {
        off = (off + 255) & ~(size_t)255;
        void* p = ws + off;
        off += bytes;
        return p;
    };
    int* alive_seq    = (int*)alloc((size_t)NROW * (LL + 1) * 4);
    int* fin_seq      = (int*)alloc((size_t)NROW * (LL + 1) * 4);
    float* alive_lp   = (float*)alloc((size_t)NROW * 4);
    float* fin_sc     = (float*)alloc((size_t)NROW * 4);
    int* fin_fl       = (int*)alloc((size_t)NROW * 4);
    float* h_buf      = (float*)alloc((size_t)NROW * DD * 4);
    float* logits     = (float*)alloc((size_t)NROW * VV * 4);
    float* ptop_val   = (float*)alloc((size_t)NROW * NCHUNK * 8 * 4);
    int* ptop_idx     = (int*)alloc((size_t)NROW * NCHUNK * 8 * 4);
    float* pmax       = (float*)alloc((size_t)NROW * NCHUNK * 4);
    float* psum       = (float*)alloc((size_t)NROW * NCHUNK * 4);
    _Float16* hfrag_hi = (_Float16*)alloc((size_t)NROW * DD * 2);
    _Float16* hfrag_lo = (_Float16*)alloc((size_t)NROW * DD * 2);
    _Float16* bfrag_hi = (_Float16*)alloc((size_t)VV * DD * 2);
    _Float16* bfrag_lo = (_Float16*)alloc((size_t)VV * DD * 2);

    k_init<<<16, 256, 0, stream>>>(initial_ids, alive_seq, alive_lp,
                                   fin_seq, fin_sc, fin_fl);
    k_bconv<<<2000, 256, 0, stream>>>(proj, bfrag_hi, bfrag_lo);
    k_hinit<<<NROW, 256, 0, stream>>>(initial_ids, init_h, embed, h_buf,
                                      hfrag_hi, hfrag_lo);
    for (int step = 0; step < LL; step++) {
        k_logits<<<500, 256, 0, stream>>>(bfrag_hi, bfrag_lo, hfrag_hi, hfrag_lo, logits);
        k_rowpart<<<dim3(NCHUNK, NROW), 256, 0, stream>>>(logits, ptop_val, ptop_idx,
                                                          pmax, psum);
        k_update<<<BB, 256, 0, stream>>>(embed, h_buf, alive_seq, alive_lp,
                                         fin_seq, fin_sc, fin_fl,
                                         ptop_val, ptop_idx, pmax, psum,
                                         hfrag_hi, hfrag_lo, step);
    }
    k_final<<<BB, 64, 0, stream>>>(alive_seq, alive_lp, fin_seq, fin_sc, fin_fl, out);
}

// Round 5
// 1675.703 us; speedup vs baseline: 5.3615x; 1.1097x over previous
//
#include <hip/hip_runtime.h>
#include <math.h>

#define BB 16
#define KK 4
#define VV 32000
#define DD 512
#define LL 32
#define EOS_ID 2
#define NEGINF 1.0e7f
#define ALPHA_C 0.6f
#define NROW (BB * KK)        // 64
#define NCHUNK 8
#define CHSZ (VV / NCHUNK)    // 4000
#define SPLIT_S 2048.0f

typedef _Float16 f16x8 __attribute__((ext_vector_type(8)));
typedef float f32x4 __attribute__((ext_vector_type(4)));

#define GLOAD_LDS16(gp, lp) \
    __builtin_amdgcn_global_load_lds( \
        (const __attribute__((address_space(1))) void*)(gp), \
        (__attribute__((address_space(3))) void*)(lp), 16, 0, 0)

// pack h value (global row r, depth d) into MFMA A-fragment order (fp16 hi/lo split)
// frag layout for mfma_f32_16x16x32_f16: lane l -> row=l&15, k = (l>>4)*8 + j
__device__ inline void pack_h(int r, int d, float v,
                              _Float16* __restrict__ hfrag_hi,
                              _Float16* __restrict__ hfrag_lo) {
    _Float16 hi = (_Float16)v;
    _Float16 lo = (_Float16)((v - (float)hi) * SPLIT_S);
    int rg = r >> 4;
    int ks = d >> 5;
    int lane = (r & 15) + 16 * ((d >> 3) & 3);
    int e = d & 7;
    int off = (((rg * 16 + ks) * 64) + lane) * 8 + e;
    hfrag_hi[off] = hi;
    hfrag_lo[off] = lo;
}

// ---------------- init: sequences / scores ----------------
__global__ void k_init(const int* __restrict__ initial_ids,
                       int* alive_seq, float* alive_lp,
                       int* fin_seq, float* fin_sc, int* fin_fl) {
    int tid = blockIdx.x * blockDim.x + threadIdx.x;
    int nthreads = gridDim.x * blockDim.x;
    const int SEQ = NROW * (LL + 1);
    for (int idx = tid; idx < SEQ; idx += nthreads) {
        int pos = idx % (LL + 1);
        int b = (idx / (LL + 1)) / KK;
        alive_seq[idx] = (pos == 0) ? initial_ids[b] : 0;
        fin_seq[idx] = 0;
    }
    for (int idx = tid; idx < NROW; idx += nthreads) {
        int k = idx % KK;
        alive_lp[idx] = (k == 0) ? 0.0f : -NEGINF;
        fin_sc[idx] = -NEGINF;
        fin_fl[idx] = 0;
    }
}

// ---------------- one-time: proj -> fp16 hi/lo B-fragments (fragment-ordered) ----------
// grid 2000 (one per col-tile ct), block 256 (4 waves; wave w does ks = w,w+4,w+8,w+12)
__global__ __launch_bounds__(256) void k_bconv(const float* __restrict__ proj,
                                               _Float16* __restrict__ bfrag_hi,
                                               _Float16* __restrict__ bfrag_lo) {
    int ct = blockIdx.x;
    int t = threadIdx.x;
    int w = t >> 6, l = t & 63;
    int col = ct * 16 + (l & 15);
    int kg = l >> 4;
    for (int ks = w; ks < 16; ks += 4) {
        int k0 = ks * 32 + kg * 8;
        f16x8 hi, lo;
        #pragma unroll
        for (int j = 0; j < 8; j++) {
            float v = proj[(size_t)(k0 + j) * VV + col];
            _Float16 h = (_Float16)v;
            hi[j] = h;
            lo[j] = (_Float16)((v - (float)h) * SPLIT_S);
        }
        size_t off = (size_t)(ct * 16 + ks) * 64 + l;
        reinterpret_cast<f16x8*>(bfrag_hi)[off] = hi;
        reinterpret_cast<f16x8*>(bfrag_lo)[off] = lo;
    }
}

// ---------------- initial h ----------------
__global__ void k_hinit(const int* __restrict__ initial_ids,
                        const float* __restrict__ init_h,
                        const float* __restrict__ embed,
                        float* __restrict__ h_buf,
                        _Float16* __restrict__ hfrag_hi,
                        _Float16* __restrict__ hfrag_lo) {
    int row = blockIdx.x;
    int b = row >> 2;
    int t = threadIdx.x;
    int tok = initial_ids[b];
    for (int d = t; d < DD; d += 256) {
        float v = tanhf(init_h[b * DD + d] + embed[(size_t)tok * DD + d]);
        h_buf[row * DD + d] = v;
        pack_h(row, d, v, hfrag_hi, hfrag_lo);
    }
}

// ---------------- logits via MFMA fp16x2 split, LDS-pipelined B ----------------
// grid 500, block 256 (4 waves). Block: all 64 rows x 64 cols (4 col-tiles).
// Wave w: row-group w (rows 16w..16w+15) x all 4 col-tiles.
// A (h-frags) preloaded to registers once; B staged 4-deep in LDS via
// global_load_lds + counted vmcnt + raw barriers (never drains to 0 mid-loop).
__global__ __launch_bounds__(256) void k_logits(
        const _Float16* __restrict__ bfrag_hi,
        const _Float16* __restrict__ bfrag_lo,
        const _Float16* __restrict__ hfrag_hi,
        const _Float16* __restrict__ hfrag_lo,
        float* __restrict__ logits) {
    int t = threadIdx.x;
    int w = t >> 6, l = t & 63;
    int ct0 = blockIdx.x * 4;
    int c0 = ct0 * 16;
    int colr = l & 15;
    int kg = l >> 4;
    int lq = l * 8;

    __shared__ _Float16 Bs[4][4][2][512];   // [slot][ct2][hi/lo][64 lanes x 8]

    // ---- A preload: this wave's row-group, all 16 k-slices, hi+lo (128 VGPRs) ----
    f16x8 ah[16], al[16];
    #pragma unroll
    for (int ks = 0; ks < 16; ks++) {
        ah[ks] = *reinterpret_cast<const f16x8*>(hfrag_hi + ((w * 16 + ks) * 64 + l) * 8);
        al[ks] = *reinterpret_cast<const f16x8*>(hfrag_lo + ((w * 16 + ks) * 64 + l) * 8);
    }
    __builtin_amdgcn_sched_barrier(0);

    f32x4 acc1[4], acc2[4];
    #pragma unroll
    for (int c2 = 0; c2 < 4; c2++) {
        acc1[c2] = (f32x4){0.f, 0.f, 0.f, 0.f};
        acc2[c2] = (f32x4){0.f, 0.f, 0.f, 0.f};
    }

    // wave w stages col-tile ct0+w's hi+lo pair for k-slice s into slot s&3
    auto stage = [&](int s) {
        const _Float16* gh = bfrag_hi + (((size_t)(ct0 + w) * 16 + s) * 64 + l) * 8;
        const _Float16* gl = bfrag_lo + (((size_t)(ct0 + w) * 16 + s) * 64 + l) * 8;
        GLOAD_LDS16(gh, &Bs[s & 3][w][0][0]);
        GLOAD_LDS16(gl, &Bs[s & 3][w][1][0]);
    };

    // prologue: fill 4 slots (per-wave 8 outstanding vm ops)
    stage(0); stage(1); stage(2); stage(3);

#define ITER(ks, NWAIT)                                                         \
    {                                                                           \
        asm volatile("s_waitcnt vmcnt(" #NWAIT ")" ::: "memory");               \
        __builtin_amdgcn_s_barrier();                                           \
        f16x8 bq[4][2];                                                         \
        _Pragma("unroll")                                                       \
        for (int c2 = 0; c2 < 4; c2++) {                                        \
            bq[c2][0] = *reinterpret_cast<const f16x8*>(&Bs[(ks) & 3][c2][0][lq]); \
            bq[c2][1] = *reinterpret_cast<const f16x8*>(&Bs[(ks) & 3][c2][1][lq]); \
        }                                                                       \
        asm volatile("s_waitcnt lgkmcnt(0)" ::: "memory");                      \
        __builtin_amdgcn_s_barrier();                                           \
        if ((ks) + 4 < 16) stage((ks) + 4);                                     \
        _Pragma("unroll")                                                       \
        for (int c2 = 0; c2 < 4; c2++) {                                        \
            acc1[c2] = __builtin_amdgcn_mfma_f32_16x16x32_f16(ah[(ks)], bq[c2][0], acc1[c2], 0, 0, 0); \
            acc2[c2] = __builtin_amdgcn_mfma_f32_16x16x32_f16(ah[(ks)], bq[c2][1], acc2[c2], 0, 0, 0); \
            acc2[c2] = __builtin_amdgcn_mfma_f32_16x16x32_f16(al[(ks)], bq[c2][0], acc2[c2], 0, 0, 0); \
        }                                                                       \
    }

    ITER(0, 6)  ITER(1, 6)  ITER(2, 6)  ITER(3, 6)
    ITER(4, 6)  ITER(5, 6)  ITER(6, 6)  ITER(7, 6)
    ITER(8, 6)  ITER(9, 6)  ITER(10, 6) ITER(11, 6)
    ITER(12, 6) ITER(13, 4) ITER(14, 2) ITER(15, 0)
#undef ITER

    // C layout: col = lane&15, row = (lane>>4)*4 + reg (dtype-independent)
    #pragma unroll
    for (int c2 = 0; c2 < 4; c2++) {
        #pragma unroll
        for (int j = 0; j < 4; j++) {
            int row = w * 16 + kg * 4 + j;
            logits[(size_t)row * VV + c0 + c2 * 16 + colr] =
                acc1[c2][j] + acc2[c2][j] * (1.0f / SPLIT_S);
        }
    }
}

// ---------------- per (row, col-chunk): stable top-8 + online max/expsum, ONE pass ----------------
// grid (NCHUNK, NROW), block 256
__global__ __launch_bounds__(256) void k_rowpart(
        const float* __restrict__ logits,
        float* __restrict__ ptop_val, int* __restrict__ ptop_idx,
        float* __restrict__ pmax, float* __restrict__ psum) {
    int chunk = blockIdx.x;
    int row = blockIdx.y;
    int t = threadIdx.x;
    int cbeg = chunk * CHSZ;
    const float4* lg4 = reinterpret_cast<const float4*>(logits + (size_t)row * VV + cbeg);

    float lv[8]; int li[8];
    #pragma unroll
    for (int j = 0; j < 8; j++) { lv[j] = -INFINITY; li[j] = 0x7fffffff; }
    float m = -INFINITY, s = 0.0f;
    for (int i = t; i < CHSZ / 4; i += 256) {
        float4 v4 = lg4[i];
        #pragma unroll
        for (int j2 = 0; j2 < 4; j2++) {
            float v = (j2 == 0) ? v4.x : (j2 == 1) ? v4.y : (j2 == 2) ? v4.z : v4.w;
            if (v > m) { s = s * expf(m - v) + 1.0f; m = v; }
            else       { s += expf(v - m); }
            if (v > lv[7]) {
                int c = cbeg + i * 4 + j2;
                int j = 7;
                while (j > 0 && v > lv[j - 1]) { lv[j] = lv[j - 1]; li[j] = li[j - 1]; j--; }
                lv[j] = v; li[j] = c;   // strict >: equal values keep earlier index first
            }
        }
    }
    __shared__ float sval[256][8];
    __shared__ int   sidx[256][8];
    __shared__ float sm[256], ss[256];
    #pragma unroll
    for (int j = 0; j < 8; j++) { sval[t][j] = lv[j]; sidx[t][j] = li[j]; }
    sm[t] = m; ss[t] = s;
    __syncthreads();
    for (int st = 128; st > 0; st >>= 1) {
        if (t < st) {
            float rv[8]; int ri[8];
            int pa = 0, pb = 0;
            #pragma unroll
            for (int j = 0; j < 8; j++) {
                bool aok = pa < 8, bok = pb < 8;
                float va = sval[t][aok ? pa : 7],     vb = sval[t + st][bok ? pb : 7];
                int   ia = sidx[t][aok ? pa : 7],     ib = sidx[t + st][bok ? pb : 7];
                bool takeA = !bok || (aok && ((va > vb) || (va == vb && ia <= ib)));
                if (takeA) { rv[j] = va; ri[j] = ia; pa++; }
                else       { rv[j] = vb; ri[j] = ib; pb++; }
            }
            #pragma unroll
            for (int j = 0; j < 8; j++) { sval[t][j] = rv[j]; sidx[t][j] = ri[j]; }
            float ma = sm[t], mb = sm[t + st];
            float M = fmaxf(ma, mb);
            ss[t] = ss[t] * expf(ma - M) + ss[t + st] * expf(mb - M);
            sm[t] = M;
        }
        __syncthreads();
    }
    if (t == 0) {
        #pragma unroll
        for (int j = 0; j < 8; j++) {
            ptop_val[(row * NCHUNK + chunk) * 8 + j] = sval[0][j];
            ptop_idx[(row * NCHUNK + chunk) * 8 + j] = sidx[0][j];
        }
        pmax[row * NCHUNK + chunk] = sm[0];
        psum[row * NCHUNK + chunk] = ss[0];
    }
}

// ---------------- beam update: fully parallel rank-based selection ----------------
// grid BB, block 256
__global__ __launch_bounds__(256) void k_update(
        const float* __restrict__ embed,
        float* h_buf, int* alive_seq, float* alive_lp,
        int* fin_seq, float* fin_sc, int* fin_fl,
        const float* __restrict__ ptop_val, const int* __restrict__ ptop_idx,
        const float* __restrict__ pmax, const float* __restrict__ psum,
        _Float16* __restrict__ hfrag_hi, _Float16* __restrict__ hfrag_lo,
        int step) {
    int b = blockIdx.x;
    int t = threadIdx.x;
    __shared__ float h_old[KK][DD];
    __shared__ int old_aseq[KK][LL + 1], old_fseq[KK][LL + 1];
    __shared__ float lse_s[KK], alp_s[KK];
    __shared__ float clp[256]; __shared__ int cidx[256];
    __shared__ float c_lp[8];  __shared__ int c_beam[8], c_id[8], c_fl[8];
    __shared__ float asc_s[8], comb_s[12]; __shared__ int combfl_s[12];
    __shared__ int sel_alive[KK], sel_fin[KK];
    __shared__ float n_alp[KK], n_fsc[KK]; __shared__ int n_ffl[KK];

    for (int idx = t; idx < KK * (LL + 1); idx += 256) {
        old_aseq[idx / (LL + 1)][idx % (LL + 1)] = alive_seq[b * KK * (LL + 1) + idx];
        old_fseq[idx / (LL + 1)][idx % (LL + 1)] = fin_seq[b * KK * (LL + 1) + idx];
    }
    for (int idx = t; idx < KK * DD; idx += 256)
        h_old[idx >> 9][idx & (DD - 1)] = h_buf[b * KK * DD + idx];
    if (t < KK) {
        int r = b * KK + t;
        float m = -INFINITY;
        #pragma unroll
        for (int c2 = 0; c2 < NCHUNK; c2++) m = fmaxf(m, pmax[r * NCHUNK + c2]);
        float s = 0.0f;
        #pragma unroll
        for (int c2 = 0; c2 < NCHUNK; c2++)
            s += psum[r * NCHUNK + c2] * expf(pmax[r * NCHUNK + c2] - m);
        lse_s[t] = m + logf(s);
        alp_s[t] = alive_lp[r];
    }
    __syncthreads();

    // 256 candidates = 4 rows x 8 chunks x 8. lp = logit - lse + alive_lp.
    {
        int row = t >> 6;
        int src = ((b * KK + row) * NCHUNK + ((t >> 3) & 7)) * 8 + (t & 7);
        clp[t] = ptop_val[src] - lse_s[row] + alp_s[row];
        cidx[t] = ptop_idx[src];
    }
    __syncthreads();
    // stable rank over all 256 (tie key = row*V + token, ascending) -> top-8
    {
        int row = t >> 6;
        float mylp = clp[t];
        int mykey = row * VV + cidx[t];
        int cnt = 0;
        for (int j = 0; j < 256; j++) {
            float lj = clp[j];
            int kj = (j >> 6) * VV + cidx[j];
            cnt += (lj > mylp) || (lj == mylp && kj < mykey);
        }
        if (cnt < 8) {
            c_lp[cnt] = mylp; c_beam[cnt] = row; c_id[cnt] = cidx[t];
            c_fl[cnt] = (cidx[t] == EOS_ID) ? 1 : 0;
        }
    }
    __syncthreads();
    if (t < 8) asc_s[t] = c_lp[t] + (c_fl[t] ? -NEGINF : 0.0f);
    if (t >= 64 && t < 76) {
        int j2 = t - 64;
        if (j2 < 4) { comb_s[j2] = fin_sc[b * KK + j2]; combfl_s[j2] = fin_fl[b * KK + j2]; }
        else {
            int cc = j2 - 4;
            float ln = powf((6.0f + (float)step) / 6.0f, ALPHA_C);
            comb_s[j2] = c_lp[cc] / ln + (c_fl[cc] ? 0.0f : -NEGINF);
            combfl_s[j2] = c_fl[cc];
        }
    }
    __syncthreads();
    if (t < 8) {   // alive: stable top-4 of asc (ties: lower position)
        float a = asc_s[t];
        int cnt = 0;
        #pragma unroll
        for (int j = 0; j < 8; j++) cnt += (asc_s[j] > a) || (asc_s[j] == a && j < t);
        if (cnt < KK) { sel_alive[cnt] = t; n_alp[cnt] = a; }
    }
    if (t >= 64 && t < 76) {  // finished: stable top-4 of comb (ties: lower position)
        int j2 = t - 64;
        float cval = comb_s[j2];
        int cnt = 0;
        #pragma unroll
        for (int j = 0; j < 12; j++) cnt += (comb_s[j] > cval) || (comb_s[j] == cval && j < j2);
        if (cnt < KK) { sel_fin[cnt] = j2; n_fsc[cnt] = cval; n_ffl[cnt] = combfl_s[j2]; }
    }
    __syncthreads();

    // write new sequences
    for (int idx = t; idx < KK * (LL + 1); idx += 256) {
        int j = idx / (LL + 1), p = idx % (LL + 1);
        int cand = sel_alive[j], bm = c_beam[cand];
        alive_seq[b * KK * (LL + 1) + idx] = (p == step + 1) ? c_id[cand] : old_aseq[bm][p];
        int src = sel_fin[j];
        int fval;
        if (src < 4) fval = old_fseq[src][p];
        else {
            int c2 = src - 4, bm2 = c_beam[c2];
            fval = (p == step + 1) ? c_id[c2] : old_aseq[bm2][p];
        }
        fin_seq[b * KK * (LL + 1) + idx] = fval;
    }
    // next-step h: h' = tanh(h_old[selected beam] + embed[new token]); also pack fp16 frags
    for (int idx = t; idx < KK * DD; idx += 256) {
        int j = idx >> 9, d = idx & (DD - 1);
        int cand = sel_alive[j], bm = c_beam[cand], tok = c_id[cand];
        float v = tanhf(h_old[bm][d] + embed[(size_t)tok * DD + d]);
        int r = b * KK + j;
        h_buf[(size_t)r * DD + d] = v;
        pack_h(r, d, v, hfrag_hi, hfrag_lo);
    }
    if (t < KK) {
        alive_lp[b * KK + t] = n_alp[t];
        fin_sc[b * KK + t] = n_fsc[t];
        fin_fl[b * KK + t] = n_ffl[t];
    }
}

// ---------------- finalize ----------------
__global__ void k_final(const int* __restrict__ alive_seq, const float* __restrict__ alive_lp,
                        const int* __restrict__ fin_seq, const float* __restrict__ fin_sc,
                        const int* __restrict__ fin_fl, float* __restrict__ out) {
    int b = blockIdx.x;
    int t = threadIdx.x;
    __shared__ int anyf;
    if (t == 0)
        anyf = fin_fl[b * KK] | fin_fl[b * KK + 1] | fin_fl[b * KK + 2] | fin_fl[b * KK + 3];
    __syncthreads();
    for (int idx = t; idx < KK * (LL + 1); idx += blockDim.x) {
        int src = anyf ? fin_seq[b * KK * (LL + 1) + idx] : alive_seq[b * KK * (LL + 1) + idx];
        out[b * KK * (LL + 1) + idx] = (float)src;
    }
    if (t < KK)
        out[BB * KK * (LL + 1) + b * KK + t] = anyf ? fin_sc[b * KK + t] : alive_lp[b * KK + t];
}

extern "C" void kernel_launch(void* const* d_in, const int* in_sizes, int n_in,
                              void* d_out, int out_size, void* d_ws, size_t ws_size,
                              hipStream_t stream) {
    const int* initial_ids = (const int*)d_in[0];
    const float* init_h = (const float*)d_in[1];
    const float* embed = (const float*)d_in[2];
    const float* proj = (const float*)d_in[3];
    float* out = (float*)d_out;

    char* ws = (char*)d_ws;
    size_t off = 0;
    auto alloc = [&](size_t bytes) -> void* {
        off = (off + 255) & ~(size_t)255;
        void* p = ws + off;
        off += bytes;
        return p;
    };
    int* alive_seq    = (int*)alloc((size_t)NROW * (LL + 1) * 4);
    int* fin_seq      = (int*)alloc((size_t)NROW * (LL + 1) * 4);
    float* alive_lp   = (float*)alloc((size_t)NROW * 4);
    float* fin_sc     = (float*)alloc((size_t)NROW * 4);
    int* fin_fl       = (int*)alloc((size_t)NROW * 4);
    float* h_buf      = (float*)alloc((size_t)NROW * DD * 4);
    float* logits     = (float*)alloc((size_t)NROW * VV * 4);
    float* ptop_val   = (float*)alloc((size_t)NROW * NCHUNK * 8 * 4);
    int* ptop_idx     = (int*)alloc((size_t)NROW * NCHUNK * 8 * 4);
    float* pmax       = (float*)alloc((size_t)NROW * NCHUNK * 4);
    float* psum       = (float*)alloc((size_t)NROW * NCHUNK * 4);
    _Float16* hfrag_hi = (_Float16*)alloc((size_t)NROW * DD * 2);
    _Float16* hfrag_lo = (_Float16*)alloc((size_t)NROW * DD * 2);
    _Float16* bfrag_hi = (_Float16*)alloc((size_t)VV * DD * 2);
    _Float16* bfrag_lo = (_Float16*)alloc((size_t)VV * DD * 2);

    k_init<<<16, 256, 0, stream>>>(initial_ids, alive_seq, alive_lp,
                                   fin_seq, fin_sc, fin_fl);
    k_bconv<<<2000, 256, 0, stream>>>(proj, bfrag_hi, bfrag_lo);
    k_hinit<<<NROW, 256, 0, stream>>>(initial_ids, init_h, embed, h_buf,
                                      hfrag_hi, hfrag_lo);
    for (int step = 0; step < LL; step++) {
        k_logits<<<500, 256, 0, stream>>>(bfrag_hi, bfrag_lo, hfrag_hi, hfrag_lo, logits);
        k_rowpart<<<dim3(NCHUNK, NROW), 256, 0, stream>>>(logits, ptop_val, ptop_idx,
                                                          pmax, psum);
        k_update<<<BB, 256, 0, stream>>>(embed, h_buf, alive_seq, alive_lp,
                                         fin_seq, fin_sc, fin_fl,
                                         ptop_val, ptop_idx, pmax, psum,
                                         hfrag_hi, hfrag_lo, step);
    }
    k_final<<<BB, 64, 0, stream>>>(alive_seq, alive_lp, fin_seq, fin_sc, fin_fl, out);
}

// Round 6
// 1469.351 us; speedup vs baseline: 6.1145x; 1.1404x over previous
//
#include <hip/hip_runtime.h>
#include <math.h>

#define BB 16
#define KK 4
#define VV 32000
#define DD 512
#define LL 32
#define EOS_ID 2
#define NEGINF 1.0e7f
#define ALPHA_C 0.6f
#define NROW (BB * KK)        // 64
#define NBLK 500              // k_logits blocks, 64 cols each
#define NSLOT 6
#define SPLIT_S 2048.0f

typedef _Float16 f16x8 __attribute__((ext_vector_type(8)));
typedef float f32x4 __attribute__((ext_vector_type(4)));

#define GLOAD_LDS16(gp, lp) \
    __builtin_amdgcn_global_load_lds( \
        (const __attribute__((address_space(1))) void*)(gp), \
        (__attribute__((address_space(3))) void*)(lp), 16, 0, 0)

// branchless stable top-8 insert (strict >: earlier/lower index wins ties).
// all private indices compile-time -> stays in VGPRs (rule #20).
#define INS8(v, idx, lv, li)                                          \
    if ((v) > lv[7]) {                                                \
        bool c_[8];                                                   \
        _Pragma("unroll")                                             \
        for (int j_ = 0; j_ < 8; j_++) c_[j_] = (v) > lv[j_];         \
        _Pragma("unroll")                                             \
        for (int j_ = 7; j_ >= 1; j_--) {                             \
            lv[j_] = c_[j_] ? (c_[j_ - 1] ? lv[j_ - 1] : (v)) : lv[j_];   \
            li[j_] = c_[j_] ? (c_[j_ - 1] ? li[j_ - 1] : (idx)) : li[j_]; \
        }                                                             \
        if (c_[0]) { lv[0] = (v); li[0] = (idx); }                    \
    }

// pack h value (global row r, depth d) into MFMA A-fragment order (fp16 hi/lo split)
__device__ inline void pack_h(int r, int d, float v,
                              _Float16* __restrict__ hfrag_hi,
                              _Float16* __restrict__ hfrag_lo) {
    _Float16 hi = (_Float16)v;
    _Float16 lo = (_Float16)((v - (float)hi) * SPLIT_S);
    int rg = r >> 4;
    int ks = d >> 5;
    int lane = (r & 15) + 16 * ((d >> 3) & 3);
    int e = d & 7;
    int off = (((rg * 16 + ks) * 64) + lane) * 8 + e;
    hfrag_hi[off] = hi;
    hfrag_lo[off] = lo;
}

// ---------------- init: sequences / scores ----------------
__global__ void k_init(const int* __restrict__ initial_ids,
                       int* alive_seq, float* alive_lp,
                       int* fin_seq, float* fin_sc, int* fin_fl) {
    int tid = blockIdx.x * blockDim.x + threadIdx.x;
    int nthreads = gridDim.x * blockDim.x;
    const int SEQ = NROW * (LL + 1);
    for (int idx = tid; idx < SEQ; idx += nthreads) {
        int pos = idx % (LL + 1);
        int b = (idx / (LL + 1)) / KK;
        alive_seq[idx] = (pos == 0) ? initial_ids[b] : 0;
        fin_seq[idx] = 0;
    }
    for (int idx = tid; idx < NROW; idx += nthreads) {
        int k = idx % KK;
        alive_lp[idx] = (k == 0) ? 0.0f : -NEGINF;
        fin_sc[idx] = -NEGINF;
        fin_fl[idx] = 0;
    }
}

// ---------------- one-time: proj -> fp16 hi/lo B-fragments ----------------
__global__ __launch_bounds__(256) void k_bconv(const float* __restrict__ proj,
                                               _Float16* __restrict__ bfrag_hi,
                                               _Float16* __restrict__ bfrag_lo) {
    int ct = blockIdx.x;
    int t = threadIdx.x;
    int w = t >> 6, l = t & 63;
    int col = ct * 16 + (l & 15);
    int kg = l >> 4;
    for (int ks = w; ks < 16; ks += 4) {
        int k0 = ks * 32 + kg * 8;
        f16x8 hi, lo;
        #pragma unroll
        for (int j = 0; j < 8; j++) {
            float v = proj[(size_t)(k0 + j) * VV + col];
            _Float16 h = (_Float16)v;
            hi[j] = h;
            lo[j] = (_Float16)((v - (float)h) * SPLIT_S);
        }
        size_t off = (size_t)(ct * 16 + ks) * 64 + l;
        reinterpret_cast<f16x8*>(bfrag_hi)[off] = hi;
        reinterpret_cast<f16x8*>(bfrag_lo)[off] = lo;
    }
}

// ---------------- initial h ----------------
__global__ void k_hinit(const int* __restrict__ initial_ids,
                        const float* __restrict__ init_h,
                        const float* __restrict__ embed,
                        float* __restrict__ h_buf,
                        _Float16* __restrict__ hfrag_hi,
                        _Float16* __restrict__ hfrag_lo) {
    int row = blockIdx.x;
    int b = row >> 2;
    int t = threadIdx.x;
    int tok = initial_ids[b];
    for (int d = t; d < DD; d += 256) {
        float v = tanhf(init_h[b * DD + d] + embed[(size_t)tok * DD + d]);
        h_buf[row * DD + d] = v;
        pack_h(row, d, v, hfrag_hi, hfrag_lo);
    }
}

// ---------------- logits via MFMA fp16x2 split + fused per-block row-reduce ---------
// grid 500, block 256 (4 waves). Block: all 64 rows x 64 cols (4 col-tiles).
// Wave w: row-group w x all 4 col-tiles. A in regs; B staged NSLOT-deep in LDS.
// Epilogue: per-row top-8 + max/expsum over this block's 64 cols -> partials.
__global__ __launch_bounds__(256) void k_logits(
        const _Float16* __restrict__ bfrag_hi,
        const _Float16* __restrict__ bfrag_lo,
        const _Float16* __restrict__ hfrag_hi,
        const _Float16* __restrict__ hfrag_lo,
        float* __restrict__ ptv, int* __restrict__ pti,
        float* __restrict__ pm, float* __restrict__ ps) {
    int t = threadIdx.x;
    int w = t >> 6, l = t & 63;
    int ct0 = blockIdx.x * 4;
    int c0 = ct0 * 16;
    int colr = l & 15;
    int kg = l >> 4;
    int lq = l * 8;

    __shared__ _Float16 Bs[NSLOT][4][2][512];   // 48 KB; reused by epilogue

    // ---- A preload: this wave's row-group, 16 k-slices, hi+lo (128 VGPRs) ----
    f16x8 ah[16], al[16];
    #pragma unroll
    for (int ks = 0; ks < 16; ks++) {
        ah[ks] = *reinterpret_cast<const f16x8*>(hfrag_hi + ((w * 16 + ks) * 64 + l) * 8);
        al[ks] = *reinterpret_cast<const f16x8*>(hfrag_lo + ((w * 16 + ks) * 64 + l) * 8);
    }
    asm volatile("s_waitcnt vmcnt(0)" ::: "memory");   // clean vmcnt for counted waits
    __builtin_amdgcn_sched_barrier(0);

    f32x4 acc1[4], acc2[4];
    #pragma unroll
    for (int c2 = 0; c2 < 4; c2++) {
        acc1[c2] = (f32x4){0.f, 0.f, 0.f, 0.f};
        acc2[c2] = (f32x4){0.f, 0.f, 0.f, 0.f};
    }

    auto stage = [&](int s) {
        int slot = s % NSLOT;
        const _Float16* gh = bfrag_hi + (((size_t)(ct0 + w) * 16 + s) * 64 + l) * 8;
        const _Float16* gl = bfrag_lo + (((size_t)(ct0 + w) * 16 + s) * 64 + l) * 8;
        GLOAD_LDS16(gh, &Bs[slot][w][0][0]);
        GLOAD_LDS16(gl, &Bs[slot][w][1][0]);
    };

    stage(0); stage(1); stage(2); stage(3); stage(4); stage(5);

#define ITER(ks, NWAIT)                                                         \
    {                                                                           \
        asm volatile("s_waitcnt vmcnt(" #NWAIT ")" ::: "memory");               \
        __builtin_amdgcn_s_barrier();                                           \
        f16x8 bq[4][2];                                                         \
        _Pragma("unroll")                                                       \
        for (int c2 = 0; c2 < 4; c2++) {                                        \
            bq[c2][0] = *reinterpret_cast<const f16x8*>(&Bs[(ks) % NSLOT][c2][0][lq]); \
            bq[c2][1] = *reinterpret_cast<const f16x8*>(&Bs[(ks) % NSLOT][c2][1][lq]); \
        }                                                                       \
        asm volatile("s_waitcnt lgkmcnt(0)" ::: "memory");                      \
        __builtin_amdgcn_s_barrier();                                           \
        if ((ks) + NSLOT < 16) stage((ks) + NSLOT);                             \
        _Pragma("unroll")                                                       \
        for (int c2 = 0; c2 < 4; c2++) {                                        \
            acc1[c2] = __builtin_amdgcn_mfma_f32_16x16x32_f16(ah[(ks)], bq[c2][0], acc1[c2], 0, 0, 0); \
            acc2[c2] = __builtin_amdgcn_mfma_f32_16x16x32_f16(ah[(ks)], bq[c2][1], acc2[c2], 0, 0, 0); \
            acc2[c2] = __builtin_amdgcn_mfma_f32_16x16x32_f16(al[(ks)], bq[c2][0], acc2[c2], 0, 0, 0); \
        }                                                                       \
    }

    ITER(0, 10)  ITER(1, 10)  ITER(2, 10)  ITER(3, 10)
    ITER(4, 10)  ITER(5, 10)  ITER(6, 10)  ITER(7, 10)
    ITER(8, 10)  ITER(9, 10)  ITER(10, 10) ITER(11, 8)
    ITER(12, 6)  ITER(13, 4)  ITER(14, 2)  ITER(15, 0)
#undef ITER

    // ---- fused row-reduce epilogue (Bs is dead; reuse as scratch pool) ----
    char* pool = (char*)&Bs[0][0][0][0];
    float* Cs  = (float*)pool;               // [64][65] = 16640 B
    float* sv  = (float*)(pool + 16640);     // [256][8]
    int*   si  = (int*)  (pool + 24832);     // [256][8]
    float* smx = (float*)(pool + 33024);     // [256]
    float* ssm = (float*)(pool + 34048);     // [256]

    // C layout: col = lane&15, row = (lane>>4)*4 + reg
    #pragma unroll
    for (int c2 = 0; c2 < 4; c2++)
        #pragma unroll
        for (int j = 0; j < 4; j++)
            Cs[(w * 16 + kg * 4 + j) * 65 + c2 * 16 + colr] =
                acc1[c2][j] + acc2[c2][j] * (1.0f / SPLIT_S);
    __syncthreads();

    int row = t >> 2, cg = t & 3;
    float lv[8]; int li[8];
    #pragma unroll
    for (int j = 0; j < 8; j++) { lv[j] = -INFINITY; li[j] = 0x7fffffff; }
    float m = -INFINITY, s = 0.0f;
    #pragma unroll
    for (int cc = 0; cc < 16; cc++) {
        float v = Cs[row * 65 + cg * 16 + cc];
        int idx = c0 + cg * 16 + cc;
        float M = fmaxf(m, v);
        s = s * expf(m - M) + expf(v - M);
        m = M;
        INS8(v, idx, lv, li)
    }
    #pragma unroll
    for (int j = 0; j < 8; j++) { sv[t * 8 + j] = lv[j]; si[t * 8 + j] = li[j]; }
    smx[t] = m; ssm[t] = s;
    __syncthreads();
    for (int st = 2; st > 0; st >>= 1) {
        if ((t & 3) < st) {
            float rv[8]; int ri[8];
            int pa = 0, pb = 0;
            #pragma unroll
            for (int j = 0; j < 8; j++) {
                bool aok = pa < 8, bok = pb < 8;
                float va = sv[t * 8 + (aok ? pa : 7)], vb = sv[(t + st) * 8 + (bok ? pb : 7)];
                int   ia = si[t * 8 + (aok ? pa : 7)], ib = si[(t + st) * 8 + (bok ? pb : 7)];
                bool takeA = !bok || (aok && ((va > vb) || (va == vb && ia <= ib)));
                if (takeA) { rv[j] = va; ri[j] = ia; pa++; }
                else       { rv[j] = vb; ri[j] = ib; pb++; }
            }
            #pragma unroll
            for (int j = 0; j < 8; j++) { sv[t * 8 + j] = rv[j]; si[t * 8 + j] = ri[j]; }
            float ma = smx[t], mb = smx[t + st];
            float M = fmaxf(ma, mb);
            ssm[t] = ssm[t] * expf(ma - M) + ssm[t + st] * expf(mb - M);
            smx[t] = M;
        }
        __syncthreads();
    }
    if ((t & 3) == 0) {
        size_t base = ((size_t)row * NBLK + blockIdx.x) * 8;
        #pragma unroll
        for (int j = 0; j < 8; j++) { ptv[base + j] = sv[t * 8 + j]; pti[base + j] = si[t * 8 + j]; }
        pm[(size_t)row * NBLK + blockIdx.x] = smx[t];
        ps[(size_t)row * NBLK + blockIdx.x] = ssm[t];
    }
}

// ---------------- merge 500 block-partials per row -> top-8 + lse ----------------
// grid NROW, block 256
__global__ __launch_bounds__(256) void k_merge(
        const float* __restrict__ ptv, const int* __restrict__ pti,
        const float* __restrict__ pm, const float* __restrict__ ps,
        float* __restrict__ rowtop_val, int* __restrict__ rowtop_idx,
        float* __restrict__ row_lse) {
    int row = blockIdx.x, t = threadIdx.x;
    __shared__ float sval[256][8]; __shared__ int sidx[256][8];
    __shared__ float sm[256], ss[256];
    const float* pv = ptv + (size_t)row * NBLK * 8;
    const int*   pi = pti + (size_t)row * NBLK * 8;

    #pragma unroll
    for (int j = 0; j < 8; j++) { sval[t][j] = pv[t * 8 + j]; sidx[t][j] = pi[t * 8 + j]; }
    float m = pm[(size_t)row * NBLK + t], s = ps[(size_t)row * NBLK + t];
    if (t + 256 < NBLK) {
        const float* bv = pv + (size_t)(t + 256) * 8;
        const int*   bi = pi + (size_t)(t + 256) * 8;
        float rv[8]; int ri[8];
        int pa = 0, pb = 0;
        #pragma unroll
        for (int j = 0; j < 8; j++) {
            bool aok = pa < 8, bok = pb < 8;
            float va = sval[t][aok ? pa : 7], vb = bv[bok ? pb : 7];
            int   ia = sidx[t][aok ? pa : 7], ib = bi[bok ? pb : 7];
            bool takeA = !bok || (aok && ((va > vb) || (va == vb && ia <= ib)));
            if (takeA) { rv[j] = va; ri[j] = ia; pa++; }
            else       { rv[j] = vb; ri[j] = ib; pb++; }
        }
        #pragma unroll
        for (int j = 0; j < 8; j++) { sval[t][j] = rv[j]; sidx[t][j] = ri[j]; }
        float mb = pm[(size_t)row * NBLK + t + 256], sb = ps[(size_t)row * NBLK + t + 256];
        float M = fmaxf(m, mb);
        s = s * expf(m - M) + sb * expf(mb - M);
        m = M;
    }
    sm[t] = m; ss[t] = s;
    __syncthreads();
    for (int st = 128; st > 0; st >>= 1) {
        if (t < st) {
            float rv[8]; int ri[8];
            int pa = 0, pb = 0;
            #pragma unroll
            for (int j = 0; j < 8; j++) {
                bool aok = pa < 8, bok = pb < 8;
                float va = sval[t][aok ? pa : 7], vb = sval[t + st][bok ? pb : 7];
                int   ia = sidx[t][aok ? pa : 7], ib = sidx[t + st][bok ? pb : 7];
                bool takeA = !bok || (aok && ((va > vb) || (va == vb && ia <= ib)));
                if (takeA) { rv[j] = va; ri[j] = ia; pa++; }
                else       { rv[j] = vb; ri[j] = ib; pb++; }
            }
            #pragma unroll
            for (int j = 0; j < 8; j++) { sval[t][j] = rv[j]; sidx[t][j] = ri[j]; }
            float ma = sm[t], mb = sm[t + st];
            float M = fmaxf(ma, mb);
            ss[t] = ss[t] * expf(ma - M) + ss[t + st] * expf(mb - M);
            sm[t] = M;
        }
        __syncthreads();
    }
    if (t == 0) {
        #pragma unroll
        for (int j = 0; j < 8; j++) {
            rowtop_val[row * 8 + j] = sval[0][j];
            rowtop_idx[row * 8 + j] = sidx[0][j];
        }
        row_lse[row] = sm[0] + logf(ss[0]);
    }
}

// ---------------- beam update: parallel rank-based selection ----------------
// grid BB, block 256
__global__ __launch_bounds__(256) void k_update(
        const float* __restrict__ embed,
        float* h_buf, int* alive_seq, float* alive_lp,
        int* fin_seq, float* fin_sc, int* fin_fl,
        const float* __restrict__ rowtop_val, const int* __restrict__ rowtop_idx,
        const float* __restrict__ row_lse,
        _Float16* __restrict__ hfrag_hi, _Float16* __restrict__ hfrag_lo,
        int step) {
    int b = blockIdx.x;
    int t = threadIdx.x;
    __shared__ float h_old[KK][DD];
    __shared__ int old_aseq[KK][LL + 1], old_fseq[KK][LL + 1];
    __shared__ float lse_s[KK], alp_s[KK];
    __shared__ float clp[32]; __shared__ int cidx[32];
    __shared__ float c_lp[8];  __shared__ int c_beam[8], c_id[8], c_fl[8];
    __shared__ float asc_s[8], comb_s[12]; __shared__ int combfl_s[12];
    __shared__ int sel_alive[KK], sel_fin[KK];
    __shared__ float n_alp[KK], n_fsc[KK]; __shared__ int n_ffl[KK];

    for (int idx = t; idx < KK * (LL + 1); idx += 256) {
        old_aseq[idx / (LL + 1)][idx % (LL + 1)] = alive_seq[b * KK * (LL + 1) + idx];
        old_fseq[idx / (LL + 1)][idx % (LL + 1)] = fin_seq[b * KK * (LL + 1) + idx];
    }
    for (int idx = t; idx < KK * DD; idx += 256)
        h_old[idx >> 9][idx & (DD - 1)] = h_buf[b * KK * DD + idx];
    if (t < KK) {
        int r = b * KK + t;
        lse_s[t] = row_lse[r];
        alp_s[t] = alive_lp[r];
    }
    __syncthreads();

    // 32 candidates = 4 rows x 8. lp = logit - lse + alive_lp.
    if (t < 32) {
        int row = t >> 3;
        int src = (b * KK + row) * 8 + (t & 7);
        clp[t] = rowtop_val[src] - lse_s[row] + alp_s[row];
        cidx[t] = rowtop_idx[src];
    }
    __syncthreads();
    if (t < 32) {   // stable rank (tie key = row*V + token) -> top-8
        int row = t >> 3;
        float mylp = clp[t];
        int mykey = row * VV + cidx[t];
        int cnt = 0;
        #pragma unroll
        for (int j = 0; j < 32; j++) {
            int kj = (j >> 3) * VV + cidx[j];
            cnt += (clp[j] > mylp) || (clp[j] == mylp && kj < mykey);
        }
        if (cnt < 8) {
            c_lp[cnt] = mylp; c_beam[cnt] = row; c_id[cnt] = cidx[t];
            c_fl[cnt] = (cidx[t] == EOS_ID) ? 1 : 0;
        }
    }
    __syncthreads();
    if (t < 8) asc_s[t] = c_lp[t] + (c_fl[t] ? -NEGINF : 0.0f);
    if (t >= 64 && t < 76) {
        int j2 = t - 64;
        if (j2 < 4) { comb_s[j2] = fin_sc[b * KK + j2]; combfl_s[j2] = fin_fl[b * KK + j2]; }
        else {
            int cc = j2 - 4;
            float ln = powf((6.0f + (float)step) / 6.0f, ALPHA_C);
            comb_s[j2] = c_lp[cc] / ln + (c_fl[cc] ? 0.0f : -NEGINF);
            combfl_s[j2] = c_fl[cc];
        }
    }
    __syncthreads();
    if (t < 8) {   // alive: stable top-4 (ties: lower position)
        float a = asc_s[t];
        int cnt = 0;
        #pragma unroll
        for (int j = 0; j < 8; j++) cnt += (asc_s[j] > a) || (asc_s[j] == a && j < t);
        if (cnt < KK) { sel_alive[cnt] = t; n_alp[cnt] = a; }
    }
    if (t >= 64 && t < 76) {  // finished: stable top-4 (ties: lower position)
        int j2 = t - 64;
        float cval = comb_s[j2];
        int cnt = 0;
        #pragma unroll
        for (int j = 0; j < 12; j++) cnt += (comb_s[j] > cval) || (comb_s[j] == cval && j < j2);
        if (cnt < KK) { sel_fin[cnt] = j2; n_fsc[cnt] = cval; n_ffl[cnt] = combfl_s[j2]; }
    }
    __syncthreads();

    for (int idx = t; idx < KK * (LL + 1); idx += 256) {
        int j = idx / (LL + 1), p = idx % (LL + 1);
        int cand = sel_alive[j], bm = c_beam[cand];
        alive_seq[b * KK * (LL + 1) + idx] = (p == step + 1) ? c_id[cand] : old_aseq[bm][p];
        int src = sel_fin[j];
        int fval;
        if (src < 4) fval = old_fseq[src][p];
        else {
            int c2 = src - 4, bm2 = c_beam[c2];
            fval = (p == step + 1) ? c_id[c2] : old_aseq[bm2][p];
        }
        fin_seq[b * KK * (LL + 1) + idx] = fval;
    }
    for (int idx = t; idx < KK * DD; idx += 256) {
        int j = idx >> 9, d = idx & (DD - 1);
        int cand = sel_alive[j], bm = c_beam[cand], tok = c_id[cand];
        float v = tanhf(h_old[bm][d] + embed[(size_t)tok * DD + d]);
        int r = b * KK + j;
        h_buf[(size_t)r * DD + d] = v;
        pack_h(r, d, v, hfrag_hi, hfrag_lo);
    }
    if (t < KK) {
        alive_lp[b * KK + t] = n_alp[t];
        fin_sc[b * KK + t] = n_fsc[t];
        fin_fl[b * KK + t] = n_ffl[t];
    }
}

// ---------------- finalize ----------------
__global__ void k_final(const int* __restrict__ alive_seq, const float* __restrict__ alive_lp,
                        const int* __restrict__ fin_seq, const float* __restrict__ fin_sc,
                        const int* __restrict__ fin_fl, float* __restrict__ out) {
    int b = blockIdx.x;
    int t = threadIdx.x;
    __shared__ int anyf;
    if (t == 0)
        anyf = fin_fl[b * KK] | fin_fl[b * KK + 1] | fin_fl[b * KK + 2] | fin_fl[b * KK + 3];
    __syncthreads();
    for (int idx = t; idx < KK * (LL + 1); idx += blockDim.x) {
        int src = anyf ? fin_seq[b * KK * (LL + 1) + idx] : alive_seq[b * KK * (LL + 1) + idx];
        out[b * KK * (LL + 1) + idx] = (float)src;
    }
    if (t < KK)
        out[BB * KK * (LL + 1) + b * KK + t] = anyf ? fin_sc[b * KK + t] : alive_lp[b * KK + t];
}

extern "C" void kernel_launch(void* const* d_in, const int* in_sizes, int n_in,
                              void* d_out, int out_size, void* d_ws, size_t ws_size,
                              hipStream_t stream) {
    const int* initial_ids = (const int*)d_in[0];
    const float* init_h = (const float*)d_in[1];
    const float* embed = (const float*)d_in[2];
    const float* proj = (const float*)d_in[3];
    float* out = (float*)d_out;

    char* ws = (char*)d_ws;
    size_t off = 0;
    auto alloc = [&](size_t bytes) -> void* {
        off = (off + 255) & ~(size_t)255;
        void* p = ws + off;
        off += bytes;
        return p;
    };
    int* alive_seq    = (int*)alloc((size_t)NROW * (LL + 1) * 4);
    int* fin_seq      = (int*)alloc((size_t)NROW * (LL + 1) * 4);
    float* alive_lp   = (float*)alloc((size_t)NROW * 4);
    float* fin_sc     = (float*)alloc((size_t)NROW * 4);
    int* fin_fl       = (int*)alloc((size_t)NROW * 4);
    float* h_buf      = (float*)alloc((size_t)NROW * DD * 4);
    float* ptv        = (float*)alloc((size_t)NROW * NBLK * 8 * 4);
    int* pti          = (int*)alloc((size_t)NROW * NBLK * 8 * 4);
    float* pm         = (float*)alloc((size_t)NROW * NBLK * 4);
    float* ps         = (float*)alloc((size_t)NROW * NBLK * 4);
    float* rowtop_val = (float*)alloc((size_t)NROW * 8 * 4);
    int* rowtop_idx   = (int*)alloc((size_t)NROW * 8 * 4);
    float* row_lse    = (float*)alloc((size_t)NROW * 4);
    _Float16* hfrag_hi = (_Float16*)alloc((size_t)NROW * DD * 2);
    _Float16* hfrag_lo = (_Float16*)alloc((size_t)NROW * DD * 2);
    _Float16* bfrag_hi = (_Float16*)alloc((size_t)VV * DD * 2);
    _Float16* bfrag_lo = (_Float16*)alloc((size_t)VV * DD * 2);

    k_init<<<16, 256, 0, stream>>>(initial_ids, alive_seq, alive_lp,
                                   fin_seq, fin_sc, fin_fl);
    k_bconv<<<2000, 256, 0, stream>>>(proj, bfrag_hi, bfrag_lo);
    k_hinit<<<NROW, 256, 0, stream>>>(initial_ids, init_h, embed, h_buf,
                                      hfrag_hi, hfrag_lo);
    for (int step = 0; step < LL; step++) {
        k_logits<<<NBLK, 256, 0, stream>>>(bfrag_hi, bfrag_lo, hfrag_hi, hfrag_lo,
                                           ptv, pti, pm, ps);
        k_merge<<<NROW, 256, 0, stream>>>(ptv, pti, pm, ps,
                                          rowtop_val, rowtop_idx, row_lse);
        k_update<<<BB, 256, 0, stream>>>(embed, h_buf, alive_seq, alive_lp,
                                         fin_seq, fin_sc, fin_fl,
                                         rowtop_val, rowtop_idx, row_lse,
                                         hfrag_hi, hfrag_lo, step);
    }
    k_final<<<BB, 64, 0, stream>>>(alive_seq, alive_lp, fin_seq, fin_sc, fin_fl, out);
}